// Round 8
// baseline (380.591 us; speedup 1.0000x reference)
//
#include <hip/hip_runtime.h>
#include <stdint.h>

typedef short short8 __attribute__((ext_vector_type(8)));
typedef float f32x4 __attribute__((ext_vector_type(4)));
typedef unsigned short u16;

#define N_TOT 32768
#define EV 4096

__device__ __forceinline__ u16 f2bf(float f){
  unsigned int x = __float_as_uint(f);
  x += 0x7FFFu + ((x >> 16) & 1u);
  return (u16)(x >> 16);
}
__device__ __forceinline__ unsigned umin_(unsigned a, unsigned b){ return a<b?a:b; }

// ---------------- Kernel A: s (fp32 + MFMA point-fragments), h (bf16); +kW fold ------
__global__ __launch_bounds__(256, 2) void kA(
    const float* __restrict__ x, const float* __restrict__ Ws,
    const float* __restrict__ bs, const float* __restrict__ Wh,
    const float* __restrict__ bh, const float* __restrict__ Wo,
    float* __restrict__ sOut, uint4* __restrict__ sfrag,
    unsigned short* __restrict__ hOut, unsigned int* __restrict__ WoT2)
{
  if (blockIdx.x >= N_TOT/64){                 // folded kW: Wo [320][256] f32 -> WoT [256][320] bf16
    const int kb = (blockIdx.x - N_TOT/64) * 32;
    const int c = threadIdx.x;
    unsigned int prev = 0;
    for (int k=0;k<32;++k){
      float v = Wo[(size_t)(kb+k)*256 + c];
      u16 h = f2bf(v);
      if (k & 1) WoT2[(size_t)c*160 + ((kb+k)>>1)] = prev | ((unsigned)h<<16);
      else       prev = (unsigned)h;
    }
    return;
  }
  __shared__ float xs[64*256];   // 64 rows, float4-chunk XOR swizzle
  const int t = threadIdx.x;
  const int r0 = blockIdx.x * 64;
  const float4* xg = (const float4*)(x + (size_t)r0*256);
  #pragma unroll
  for (int i=0;i<16;++i){
    int f = t + 256*i;
    int row = f >> 6, c4 = f & 63;
    float4 v = xg[f];
    *(float4*)&xs[row*256 + (c4 ^ (row&7))*4] = v;
  }
  __syncthreads();
  // s: fp32. thread: row = t>>2, k-quarter = t&3 ; reduce across k-quarters via shfl.
  {
    int row = t >> 2, kq = t & 3;
    float a0=0.f,a1=0.f,a2=0.f,a3=0.f;
    const float4* wsr = (const float4*)Ws;   // Ws[k][0..3]
    #pragma unroll 4
    for (int i=0;i<16;++i){
      int c4 = kq*16 + i;
      float4 xv = *(const float4*)&xs[row*256 + (c4 ^ (row&7))*4];
      float4 w0 = wsr[c4*4+0], w1 = wsr[c4*4+1], w2 = wsr[c4*4+2], w3 = wsr[c4*4+3];
      a0 += xv.x*w0.x + xv.y*w1.x + xv.z*w2.x + xv.w*w3.x;
      a1 += xv.x*w0.y + xv.y*w1.y + xv.z*w2.y + xv.w*w3.y;
      a2 += xv.x*w0.z + xv.y*w1.z + xv.z*w2.z + xv.w*w3.z;
      a3 += xv.x*w0.w + xv.y*w1.w + xv.z*w2.w + xv.w*w3.w;
    }
    a0 += __shfl_xor(a0,1); a0 += __shfl_xor(a0,2);
    a1 += __shfl_xor(a1,1); a1 += __shfl_xor(a1,2);
    a2 += __shfl_xor(a2,1); a2 += __shfl_xor(a2,2);
    a3 += __shfl_xor(a3,1); a3 += __shfl_xor(a3,2);
    if (kq == 0){
      float4 sv = { a0+bs[0], a1+bs[1], a2+bs[2], a3+bs[3] };
      ((float4*)sOut)[r0 + row] = sv;
      // A-side (point) fragment: k0-7 = [hi4,hi4]; k8-15 = [lo4, nh, nl, 1, 1]
      u16 h0=f2bf(sv.x), h1=f2bf(sv.y), h2=f2bf(sv.z), h3=f2bf(sv.w);
      float e0 = sv.x - __uint_as_float((unsigned)h0<<16);
      float e1 = sv.y - __uint_as_float((unsigned)h1<<16);
      float e2 = sv.z - __uint_as_float((unsigned)h2<<16);
      float e3 = sv.w - __uint_as_float((unsigned)h3<<16);
      u16 l0=f2bf(e0), l1=f2bf(e1), l2=f2bf(e2), l3=f2bf(e3);
      float n = sv.x*sv.x + sv.y*sv.y + sv.z*sv.z + sv.w*sv.w;
      u16 nh = f2bf(n);
      u16 nl = f2bf(n - __uint_as_float((unsigned)nh<<16));
      uint4 w0, w1;
      w0.x = (unsigned)h0 | ((unsigned)h1<<16);
      w0.y = (unsigned)h2 | ((unsigned)h3<<16);
      w0.z = w0.x; w0.w = w0.y;
      w1.x = (unsigned)l0 | ((unsigned)l1<<16);
      w1.y = (unsigned)l2 | ((unsigned)l3<<16);
      w1.z = (unsigned)nh | ((unsigned)nl<<16);
      w1.w = 0x3F803F80u;                       // 1.0, 1.0 (pairs with B's si2 hi/lo)
      sfrag[(size_t)(r0+row)*2 + 0] = w0;
      sfrag[(size_t)(r0+row)*2 + 1] = w1;
    }
  }
  // h: row = t&63, col-group (4 cols) = wave + 4*rd
  const float4* whr = (const float4*)Wh;   // Wh[k][32]
  #pragma unroll
  for (int rd=0; rd<2; ++rd){
    int row = t & 63;
    int cg = (t >> 6) + rd*4;
    int cgu = __builtin_amdgcn_readfirstlane(cg);
    float a0=0.f,a1=0.f,a2=0.f,a3=0.f;
    #pragma unroll 4
    for (int c4=0;c4<64;++c4){
      float4 xv = *(const float4*)&xs[row*256 + (c4 ^ (row&7))*4];
      float4 w0 = whr[(c4*4+0)*8 + cgu];
      float4 w1 = whr[(c4*4+1)*8 + cgu];
      float4 w2 = whr[(c4*4+2)*8 + cgu];
      float4 w3 = whr[(c4*4+3)*8 + cgu];
      a0 += xv.x*w0.x + xv.y*w1.x + xv.z*w2.x + xv.w*w3.x;
      a1 += xv.x*w0.y + xv.y*w1.y + xv.z*w2.y + xv.w*w3.y;
      a2 += xv.x*w0.z + xv.y*w1.z + xv.z*w2.z + xv.w*w3.z;
      a3 += xv.x*w0.w + xv.y*w1.w + xv.z*w2.w + xv.w*w3.w;
    }
    float4 bv = ((const float4*)bh)[cgu];
    ushort4 hb = { f2bf(a0+bv.x), f2bf(a1+bv.y), f2bf(a2+bv.z), f2bf(a3+bv.w) };
    *(ushort4*)&hOut[(size_t)(r0+row)*32 + cgu*4] = hb;
  }
}

// ---------------- Kernel B: half-sample radix-select + slist + exact final (safe) ----
// 2048 blocks; block: 16 queries, 4 waves each scanning a 1024-pt quarter.
// Pass 1 (32 tiles/wave = half sample): MFMA d^2 -> 128-bin clamped exponent histogram
//   with in-lane atomic combining.  Prefix -> tau (subset tau is a valid upper bound).
// Pass 2 (64 tiles/wave): push survivor indices (u < tau) to slist; scnt counts ALL.
// Final (wave 0): if scnt<=SCAP exact d^2 on survivors, else exact full-scan fallback.
#define BUBBLE16(v)                                              \
  { _Pragma("unroll")                                            \
    for (int k=0;k<16;++k){                                      \
      unsigned int mn = (v) < bp[k] ? (v) : bp[k];               \
      unsigned int mx = (v) < bp[k] ? bp[k] : (v);               \
      bp[k] = mn; (v) = mx;                                      \
    } }

#define MERGE16(OT)                                              \
  { unsigned int c[16];                                          \
    _Pragma("unroll")                                            \
    for (int k=0;k<16;++k){ unsigned int b2 = (OT)[15-k];        \
      c[k] = bp[k] < b2 ? bp[k] : b2; }                          \
    _Pragma("unroll")                                            \
    for (int d=8; d>=1; d>>=1){                                  \
      _Pragma("unroll")                                          \
      for (int i=0;i<16;++i){                                    \
        if ((i & d) == 0){                                       \
          unsigned int lo = c[i] < c[i+d] ? c[i] : c[i+d];       \
          unsigned int hi = c[i] < c[i+d] ? c[i+d] : c[i];       \
          c[i] = lo; c[i+d] = hi;                                \
        }                                                        \
      }                                                          \
    }                                                            \
    _Pragma("unroll")                                            \
    for (int k=0;k<16;++k) bp[k] = c[k]; }

#define SCAP 384

__global__ __launch_bounds__(256, 8) void kB(
    const float* __restrict__ sIn, const uint4* __restrict__ sfrag,
    const unsigned short* __restrict__ hIn, unsigned short* __restrict__ Umini)
{
  __shared__ unsigned int hist[16*129];    // per-query 128 bins (exp clamp 64..191), stride 129
  __shared__ u16 slist[16*SCAP];           // per-query survivor indices
  __shared__ unsigned int scnt[16];
  __shared__ unsigned int tauL[16];
  __shared__ unsigned int mrg[48][17];     // cross-wave merge lists (waves 1-3)
  const int t = threadIdx.x;
  const int wv = t >> 6, l = t & 63;
  const int e = blockIdx.x >> 8;           // 256 blocks/event
  const int qblk = (blockIdx.x & 255) * 16;
  const int q16 = l & 15, g = l >> 4;
  const int qloc = qblk + q16;

  const float4* sg = (const float4*)sIn;
  const float4 sq = sg[(size_t)e*EV + qloc];
  const float si2 = sq.x*sq.x + sq.y*sq.y + sq.z*sq.z + sq.w*sq.w;

  // B (query) fragment: g0: [-2s hi4 | -2s lo4]; g1: [-2s hi4 | 1, 1, si2h, si2l]
  union BU { u16 u[8]; short8 v; } bu;
  #pragma unroll
  for (int i2=0;i2<8;++i2) bu.u[i2]=0;
  {
    float tx=-2.f*sq.x, ty=-2.f*sq.y, tz=-2.f*sq.z, tw=-2.f*sq.w;
    u16 h0=f2bf(tx), h1=f2bf(ty), h2=f2bf(tz), h3=f2bf(tw);
    if (g==0){
      float e0 = tx - __uint_as_float((unsigned)h0<<16);
      float e1 = ty - __uint_as_float((unsigned)h1<<16);
      float e2 = tz - __uint_as_float((unsigned)h2<<16);
      float e3 = tw - __uint_as_float((unsigned)h3<<16);
      bu.u[0]=h0; bu.u[1]=h1; bu.u[2]=h2; bu.u[3]=h3;
      bu.u[4]=f2bf(e0); bu.u[5]=f2bf(e1); bu.u[6]=f2bf(e2); bu.u[7]=f2bf(e3);
    } else if (g==1){
      u16 sh = f2bf(si2);
      u16 sl = f2bf(si2 - __uint_as_float((unsigned)sh<<16));
      bu.u[0]=h0; bu.u[1]=h1; bu.u[2]=h2; bu.u[3]=h3;
      bu.u[4]=0x3F80; bu.u[5]=0x3F80; bu.u[6]=sh; bu.u[7]=sl;
    }
  }
  const short8 bq = bu.v;

  // zero histogram
  for (int i=t; i<16*129; i+=256) hist[i]=0;
  __syncthreads();

  const f32x4 zacc = {0.f,0.f,0.f,0.f};
  const uint4 zf4 = {0,0,0,0};
  const uint4* fw = sfrag + (((size_t)e*EV + wv*1024) << 1);
  const int a32 = q16*2 + g;               // lanes 0-31 load the 2 uint4 halves of point q16
  const bool ld = (l < 32);
  const int hbase = q16*129;

  // ---- pass 1: 128-bin histogram over first 512 pts of this wave's quarter ----
  {
    uint4 f0 = ld ? fw[a32]      : zf4;
    uint4 f1 = ld ? fw[32 + a32] : zf4;
    uint4 f2 = ld ? fw[64 + a32] : zf4;
    for (int tl=0; tl<32; ++tl){
      uint4 fn = zf4;
      if (ld && tl+3 < 32) fn = fw[(size_t)(tl+3)*32 + a32];
      union { uint4 q; short8 v; } au; au.q = f0;
      f32x4 acc = __builtin_amdgcn_mfma_f32_16x16x32_bf16(au.v, bq, zacc, 0,0,0);
      f0 = f1; f1 = f2; f2 = fn;
      unsigned b4[4];
      #pragma unroll
      for (int rg=0; rg<4; ++rg){
        unsigned u = __float_as_uint(fmaxf(acc[rg],0.f));
        unsigned ex = u >> 23;
        b4[rg] = umin_(191u, ex < 64u ? 64u : ex) - 64u;
      }
      // in-lane first-occurrence combine: 1-4 atomics instead of 4
      unsigned a0 = 1u + (b4[1]==b4[0]) + (b4[2]==b4[0]) + (b4[3]==b4[0]);
      bool f1o = (b4[1]!=b4[0]);
      bool f2o = (b4[2]!=b4[0]) && (b4[2]!=b4[1]);
      bool f3o = (b4[3]!=b4[0]) && (b4[3]!=b4[1]) && (b4[3]!=b4[2]);
      unsigned a1 = 1u + (b4[2]==b4[1]) + (b4[3]==b4[1]);
      unsigned a2 = 1u + (b4[3]==b4[2]);
      atomicAdd(&hist[hbase + b4[0]], a0);
      if (f1o) atomicAdd(&hist[hbase + b4[1]], a1);
      if (f2o) atomicAdd(&hist[hbase + b4[2]], a2);
      if (f3o) atomicAdd(&hist[hbase + b4[3]], 1u);
    }
  }
  __syncthreads();

  // ---- prefix: find tau per query (16 threads per query, chunks of 8 bins) ----
  {
    int q = t >> 4, i = t & 15;
    int base = q*129 + i*8;
    unsigned cs = 0;
    #pragma unroll
    for (int k2=0;k2<8;++k2) cs += hist[base+k2];
    unsigned ps = cs;
    #pragma unroll
    for (int d=1; d<16; d<<=1){
      unsigned o = __shfl_up(ps, d, 16);
      if ((t&15) >= d) ps += o;
    }
    if (ps >= 16u && (ps - cs) < 16u){
      unsigned run = ps - cs;
      unsigned B = 127;
      #pragma unroll
      for (int k2=0;k2<8;++k2){
        unsigned c2 = hist[base+k2];
        bool hit = (run < 16u) && (run + c2 >= 16u);
        if (hit) B = (unsigned)(i*8 + k2);
        run += c2;
      }
      tauL[q] = (B >= 127u) ? 0x7F800001u : ((B + 65u) << 23);
      scnt[q] = 0;
    }
  }
  __syncthreads();
  const unsigned tauB = tauL[q16];

  // ---- pass 2: full quarter scan, push survivor indices (scnt counts ALL) ----
  {
    uint4 f0 = ld ? fw[a32]      : zf4;
    uint4 f1 = ld ? fw[32 + a32] : zf4;
    uint4 f2 = ld ? fw[64 + a32] : zf4;
    int jt = wv*1024 + g*4;
    for (int tl=0; tl<64; ++tl){
      uint4 fn = zf4;
      if (ld && tl+3 < 64) fn = fw[(size_t)(tl+3)*32 + a32];
      union { uint4 q; short8 v; } au; au.q = f0;
      f32x4 acc = __builtin_amdgcn_mfma_f32_16x16x32_bf16(au.v, bq, zacc, 0,0,0);
      f0 = f1; f1 = f2; f2 = fn;
      #pragma unroll
      for (int rg=0; rg<4; ++rg){
        unsigned u = __float_as_uint(fmaxf(acc[rg],0.f));
        if (u < tauB){
          unsigned idx = atomicAdd(&scnt[q16], 1u);
          if (idx < (unsigned)SCAP) slist[q16*SCAP + idx] = (u16)(jt + rg);
        }
      }
      jt += 16;
    }
  }
  __syncthreads();
  if (wv != 0) return;   // final phase: wave 0 only, no barriers below

  // ---- final: exact fp32 d^2 -> top-16 (survivors, or full-scan fallback) ----
  unsigned scn_raw = scnt[q16];
  unsigned int bp[16];
  #pragma unroll
  for (int k=0;k<16;++k) bp[k]=0xFFFFFFFFu;
  if (scn_raw > (unsigned)SCAP){
    // overflow fallback: exact scan of all EV points (correctness guarantee)
    for (int jj=g; jj<EV; jj+=4){
      float4 s4 = sg[(size_t)e*EV + jj];
      float dx = sq.x-s4.x, dy = sq.y-s4.y, dz = sq.z-s4.z, dw = sq.w-s4.w;
      float d2 = dx*dx + dy*dy + dz*dz + dw*dw;
      unsigned key = (__float_as_uint(d2) & 0xFFFFF000u) | (unsigned)jj;
      if (key < bp[15]) { BUBBLE16(key) }
    }
  } else {
    for (unsigned i=g; i<scn_raw; i+=4){
      int jj = (int)slist[q16*SCAP + i];
      float4 s4 = sg[(size_t)e*EV + jj];
      float dx = sq.x-s4.x, dy = sq.y-s4.y, dz = sq.z-s4.z, dw = sq.w-s4.w;
      float d2 = dx*dx + dy*dy + dz*dz + dw*dw;
      unsigned key = (__float_as_uint(d2) & 0xFFFFF000u) | (unsigned)jj;
      BUBBLE16(key)
    }
  }

  // merge across the 4 rowgrp-lanes of each query (xor 16, then xor 32)
  #pragma unroll
  for (int st=0; st<2; ++st){
    const int msk = (st==0) ? 16 : 32;
    unsigned int ot[16];
    #pragma unroll
    for (int k=0;k<16;++k) ot[k] = (unsigned int)__shfl_xor((int)bp[k], msk, 64);
    MERGE16(ot)
  }

  // aggregation: lane (q16, g) owns features g*8..g*8+7 for all 16 neighbors
  float am[8], ax[8];
  #pragma unroll
  for (int p=0;p<8;++p){ am[p]=0.f; ax[p]=-3.4e38f; }
  const uint4* hb = (const uint4*)(hIn + (size_t)e*EV*32);
  #pragma unroll
  for (int i=0;i<16;++i){
    unsigned int key = bp[i];
    int j = (int)(key & 0xFFFu);
    float d2 = __uint_as_float(key & 0xFFFFF000u);
    float w = __expf(-10.f * d2);
    uint4 hv = hb[(size_t)j*4 + g];
    unsigned int uu[4] = {hv.x, hv.y, hv.z, hv.w};
    #pragma unroll
    for (int c2=0;c2<4;++c2){
      float flo = __uint_as_float(uu[c2] << 16);
      float fhi = __uint_as_float(uu[c2] & 0xFFFF0000u);
      float m0 = w*flo, m1 = w*fhi;
      am[c2*2]   += m0;                 am[c2*2+1] += m1;
      ax[c2*2]    = fmaxf(ax[c2*2],m0); ax[c2*2+1]  = fmaxf(ax[c2*2+1],m1);
    }
  }
  {
    unsigned short* Ur = Umini + ((size_t)e*EV + qloc)*64;
    uint4 pm, px;
    pm.x = (unsigned)f2bf(am[0]*(1.f/16.f)) | ((unsigned)f2bf(am[1]*(1.f/16.f))<<16);
    pm.y = (unsigned)f2bf(am[2]*(1.f/16.f)) | ((unsigned)f2bf(am[3]*(1.f/16.f))<<16);
    pm.z = (unsigned)f2bf(am[4]*(1.f/16.f)) | ((unsigned)f2bf(am[5]*(1.f/16.f))<<16);
    pm.w = (unsigned)f2bf(am[6]*(1.f/16.f)) | ((unsigned)f2bf(am[7]*(1.f/16.f))<<16);
    px.x = (unsigned)f2bf(ax[0]) | ((unsigned)f2bf(ax[1])<<16);
    px.y = (unsigned)f2bf(ax[2]) | ((unsigned)f2bf(ax[3])<<16);
    px.z = (unsigned)f2bf(ax[4]) | ((unsigned)f2bf(ax[5])<<16);
    px.w = (unsigned)f2bf(ax[6]) | ((unsigned)f2bf(ax[7])<<16);
    *(uint4*)(Ur +  0 + g*8) = pm;
    *(uint4*)(Ur + 32 + g*8) = px;
  }
}

// ---------------- Kernel C: x_new = [bf16(x)|Umini] @ Wo + bo ; residual ; LayerNorm ----
__global__ __launch_bounds__(256, 4) void kC(
    const unsigned short* __restrict__ Umini, const unsigned short* __restrict__ WoT,
    const float* __restrict__ bo, const float* __restrict__ x,
    const float* __restrict__ gamma, const float* __restrict__ beta,
    float* __restrict__ out)
{
  __shared__ unsigned short At[64*40];    // [64 rows][32k padded to 40]
  __shared__ unsigned short Bt[256*40];   // [256 cols][32k padded to 40]
  __shared__ float ps[64*4], pq[64*4];
  const int t = threadIdx.x;
  const int r0 = blockIdx.x * 64;
  const int l = t & 63, wv = t >> 6;
  const int lq = l & 15, g = l >> 4;
  f32x4 acc[4][4];
  const f32x4 zero = {0.f,0.f,0.f,0.f};
  #pragma unroll
  for (int m=0;m<4;++m)
    #pragma unroll
    for (int n=0;n<4;++n) acc[m][n] = zero;

  for (int kk=0; kk<10; ++kk){
    const int k0 = kk*32;
    __syncthreads();
    { // stage A: k<256 from x (fp32 -> bf16 via v_cvt_pk), else from Umini
      int row = t >> 2, ko = (t & 3)*8;
      uint4 av;
      if (k0 < 256){
        const float4* xr = (const float4*)(x + (size_t)(r0+row)*256 + k0 + ko);
        float4 u0 = xr[0], u1 = xr[1];
        unsigned p0,p1,p2,p3;
        asm("v_cvt_pk_bf16_f32 %0, %1, %2" : "=v"(p0) : "v"(u0.x), "v"(u0.y));
        asm("v_cvt_pk_bf16_f32 %0, %1, %2" : "=v"(p1) : "v"(u0.z), "v"(u0.w));
        asm("v_cvt_pk_bf16_f32 %0, %1, %2" : "=v"(p2) : "v"(u1.x), "v"(u1.y));
        asm("v_cvt_pk_bf16_f32 %0, %1, %2" : "=v"(p3) : "v"(u1.z), "v"(u1.w));
        av.x = p0; av.y = p1; av.z = p2; av.w = p3;
      } else {
        av = *(const uint4*)(Umini + (size_t)(r0+row)*64 + (k0-256) + ko);
      }
      *(uint4*)(At + row*40 + ko) = av;
    }
    { // stage B^T from pre-transposed WoT [256 cols][320 k] bf16
      int col = t;
      const uint4* src = (const uint4*)(WoT + (size_t)col*320 + k0);
      #pragma unroll
      for (int j=0;j<4;++j) *(uint4*)(Bt + col*40 + j*8) = src[j];
    }
    __syncthreads();
    short8 a[4], b[4];
    #pragma unroll
    for (int m=0;m<4;++m) a[m] = *(const short8*)(At + (16*m+lq)*40 + g*8);
    #pragma unroll
    for (int n=0;n<4;++n) b[n] = *(const short8*)(Bt + (wv*64 + 16*n + lq)*40 + g*8);
    #pragma unroll
    for (int m=0;m<4;++m)
      #pragma unroll
      for (int n=0;n<4;++n)
        acc[m][n] = __builtin_amdgcn_mfma_f32_16x16x32_bf16(a[m], b[n], acc[m][n], 0, 0, 0);
  }

  // epilogue: + bo + x(residual), LayerNorm over 256 cols
  float bo_n[4], ga_n[4], be_n[4];
  #pragma unroll
  for (int n=0;n<4;++n){
    int colg = wv*64 + 16*n + lq;
    bo_n[n] = bo[colg]; ga_n[n] = gamma[colg]; be_n[n] = beta[colg];
  }
  float pr[4][4], pr2[4][4];
  #pragma unroll
  for (int m=0;m<4;++m){
    #pragma unroll
    for (int rg=0;rg<4;++rg){
      int rowg = r0 + 16*m + g*4 + rg;
      float sum=0.f, sq=0.f;
      #pragma unroll
      for (int n=0;n<4;++n){
        int colg = wv*64 + 16*n + lq;
        float y = acc[m][n][rg] + bo_n[n] + x[(size_t)rowg*256 + colg];
        acc[m][n][rg] = y;
        sum += y; sq += y*y;
      }
      sum += __shfl_xor(sum,1); sq += __shfl_xor(sq,1);
      sum += __shfl_xor(sum,2); sq += __shfl_xor(sq,2);
      sum += __shfl_xor(sum,4); sq += __shfl_xor(sq,4);
      sum += __shfl_xor(sum,8); sq += __shfl_xor(sq,8);
      pr[m][rg]=sum; pr2[m][rg]=sq;
    }
  }
  if (lq == 0){
    #pragma unroll
    for (int m=0;m<4;++m)
      #pragma unroll
      for (int rg=0;rg<4;++rg){
        int rowl = 16*m + g*4 + rg;
        ps[rowl*4 + wv] = pr[m][rg];
        pq[rowl*4 + wv] = pr2[m][rg];
      }
  }
  __syncthreads();
  #pragma unroll
  for (int m=0;m<4;++m){
    #pragma unroll
    for (int rg=0;rg<4;++rg){
      int rowl = 16*m + g*4 + rg;
      float sum = ps[rowl*4+0]+ps[rowl*4+1]+ps[rowl*4+2]+ps[rowl*4+3];
      float sq  = pq[rowl*4+0]+pq[rowl*4+1]+pq[rowl*4+2]+pq[rowl*4+3];
      float mu  = sum * (1.f/256.f);
      float var = sq * (1.f/256.f) - mu*mu;
      float inv = rsqrtf(var + 1e-5f);
      int rowg = r0 + rowl;
      #pragma unroll
      for (int n=0;n<4;++n){
        int colg = wv*64 + 16*n + lq;
        out[(size_t)rowg*256 + colg] = ga_n[n]*(acc[m][n][rg] - mu)*inv + be_n[n];
      }
    }
  }
}

extern "C" void kernel_launch(void* const* d_in, const int* in_sizes, int n_in,
                              void* d_out, int out_size, void* d_ws, size_t ws_size,
                              hipStream_t stream)
{
  const float* x     = (const float*)d_in[0];
  // d_in[1] = batch_index (block-sorted equal events; unused)
  const float* Ws    = (const float*)d_in[2];
  const float* bs    = (const float*)d_in[3];
  const float* Wh    = (const float*)d_in[4];
  const float* bh    = (const float*)d_in[5];
  const float* Wo    = (const float*)d_in[6];
  const float* bo    = (const float*)d_in[7];
  const float* gamma = (const float*)d_in[8];
  const float* beta  = (const float*)d_in[9];
  float* out = (float*)d_out;

  char* ws = (char*)d_ws;
  float*          sBuf  = (float*)ws;                        // N*4 f32    = 0.5 MB
  uint4*          sfrag = (uint4*)(ws + 524288);             // N*32 B     = 1 MB
  unsigned short* hBuf  = (unsigned short*)(ws + 1572864);   // N*32 bf16  = 2 MB
  unsigned short* Umini = (unsigned short*)(ws + 3670016);   // N*64 bf16  = 4 MB
  unsigned short* WoT   = (unsigned short*)(ws + 7864320);   // 256*320 bf16 = 160 KB

  kA<<<dim3(N_TOT/64 + 10), dim3(256), 0, stream>>>(x, Ws, bs, Wh, bh, Wo,
                                                    sBuf, sfrag, hBuf, (unsigned int*)WoT);
  kB<<<dim3(N_TOT/16), dim3(256), 0, stream>>>(sBuf, sfrag, hBuf, Umini);
  kC<<<dim3(N_TOT/64), dim3(256), 0, stream>>>(Umini, WoT, bo, x, gamma, beta, out);
}

// Round 9
// 246.464 us; speedup vs baseline: 1.5442x; 1.5442x over previous
//
#include <hip/hip_runtime.h>
#include <stdint.h>

typedef short short8 __attribute__((ext_vector_type(8)));
typedef float f32x4 __attribute__((ext_vector_type(4)));
typedef unsigned short u16;

#define N_TOT 32768
#define EV 4096

__device__ __forceinline__ u16 f2bf(float f){
  unsigned int x = __float_as_uint(f);
  x += 0x7FFFu + ((x >> 16) & 1u);
  return (u16)(x >> 16);
}
__device__ __forceinline__ unsigned umin_(unsigned a, unsigned b){ return a<b?a:b; }

// ---------------- Kernel A: s (fp32 + MFMA point-fragments), h (bf16); +kW fold ------
__global__ __launch_bounds__(256, 2) void kA(
    const float* __restrict__ x, const float* __restrict__ Ws,
    const float* __restrict__ bs, const float* __restrict__ Wh,
    const float* __restrict__ bh, const float* __restrict__ Wo,
    float* __restrict__ sOut, uint4* __restrict__ sfrag,
    unsigned short* __restrict__ hOut, unsigned int* __restrict__ WoT2)
{
  if (blockIdx.x >= N_TOT/64){                 // folded kW: Wo [320][256] f32 -> WoT [256][320] bf16
    const int kb = (blockIdx.x - N_TOT/64) * 32;
    const int c = threadIdx.x;
    unsigned int prev = 0;
    for (int k=0;k<32;++k){
      float v = Wo[(size_t)(kb+k)*256 + c];
      u16 h = f2bf(v);
      if (k & 1) WoT2[(size_t)c*160 + ((kb+k)>>1)] = prev | ((unsigned)h<<16);
      else       prev = (unsigned)h;
    }
    return;
  }
  __shared__ float xs[64*256];   // 64 rows, float4-chunk XOR swizzle
  const int t = threadIdx.x;
  const int r0 = blockIdx.x * 64;
  const float4* xg = (const float4*)(x + (size_t)r0*256);
  #pragma unroll
  for (int i=0;i<16;++i){
    int f = t + 256*i;
    int row = f >> 6, c4 = f & 63;
    float4 v = xg[f];
    *(float4*)&xs[row*256 + (c4 ^ (row&7))*4] = v;
  }
  __syncthreads();
  // s: fp32. thread: row = t>>2, k-quarter = t&3 ; reduce across k-quarters via shfl.
  {
    int row = t >> 2, kq = t & 3;
    float a0=0.f,a1=0.f,a2=0.f,a3=0.f;
    const float4* wsr = (const float4*)Ws;   // Ws[k][0..3]
    #pragma unroll 4
    for (int i=0;i<16;++i){
      int c4 = kq*16 + i;
      float4 xv = *(const float4*)&xs[row*256 + (c4 ^ (row&7))*4];
      float4 w0 = wsr[c4*4+0], w1 = wsr[c4*4+1], w2 = wsr[c4*4+2], w3 = wsr[c4*4+3];
      a0 += xv.x*w0.x + xv.y*w1.x + xv.z*w2.x + xv.w*w3.x;
      a1 += xv.x*w0.y + xv.y*w1.y + xv.z*w2.y + xv.w*w3.y;
      a2 += xv.x*w0.z + xv.y*w1.z + xv.z*w2.z + xv.w*w3.z;
      a3 += xv.x*w0.w + xv.y*w1.w + xv.z*w2.w + xv.w*w3.w;
    }
    a0 += __shfl_xor(a0,1); a0 += __shfl_xor(a0,2);
    a1 += __shfl_xor(a1,1); a1 += __shfl_xor(a1,2);
    a2 += __shfl_xor(a2,1); a2 += __shfl_xor(a2,2);
    a3 += __shfl_xor(a3,1); a3 += __shfl_xor(a3,2);
    if (kq == 0){
      float4 sv = { a0+bs[0], a1+bs[1], a2+bs[2], a3+bs[3] };
      ((float4*)sOut)[r0 + row] = sv;
      // A-side (point) fragment: k0-7 = [hi4,hi4]; k8-15 = [lo4, nh, nl, 1, 1]
      u16 h0=f2bf(sv.x), h1=f2bf(sv.y), h2=f2bf(sv.z), h3=f2bf(sv.w);
      float e0 = sv.x - __uint_as_float((unsigned)h0<<16);
      float e1 = sv.y - __uint_as_float((unsigned)h1<<16);
      float e2 = sv.z - __uint_as_float((unsigned)h2<<16);
      float e3 = sv.w - __uint_as_float((unsigned)h3<<16);
      u16 l0=f2bf(e0), l1=f2bf(e1), l2=f2bf(e2), l3=f2bf(e3);
      float n = sv.x*sv.x + sv.y*sv.y + sv.z*sv.z + sv.w*sv.w;
      u16 nh = f2bf(n);
      u16 nl = f2bf(n - __uint_as_float((unsigned)nh<<16));
      uint4 w0, w1;
      w0.x = (unsigned)h0 | ((unsigned)h1<<16);
      w0.y = (unsigned)h2 | ((unsigned)h3<<16);
      w0.z = w0.x; w0.w = w0.y;
      w1.x = (unsigned)l0 | ((unsigned)l1<<16);
      w1.y = (unsigned)l2 | ((unsigned)l3<<16);
      w1.z = (unsigned)nh | ((unsigned)nl<<16);
      w1.w = 0x3F803F80u;                       // 1.0, 1.0 (pairs with B's si2 hi/lo)
      sfrag[(size_t)(r0+row)*2 + 0] = w0;
      sfrag[(size_t)(r0+row)*2 + 1] = w1;
    }
  }
  // h: row = t&63, col-group (4 cols) = wave + 4*rd
  const float4* whr = (const float4*)Wh;   // Wh[k][32]
  #pragma unroll
  for (int rd=0; rd<2; ++rd){
    int row = t & 63;
    int cg = (t >> 6) + rd*4;
    int cgu = __builtin_amdgcn_readfirstlane(cg);
    float a0=0.f,a1=0.f,a2=0.f,a3=0.f;
    #pragma unroll 4
    for (int c4=0;c4<64;++c4){
      float4 xv = *(const float4*)&xs[row*256 + (c4 ^ (row&7))*4];
      float4 w0 = whr[(c4*4+0)*8 + cgu];
      float4 w1 = whr[(c4*4+1)*8 + cgu];
      float4 w2 = whr[(c4*4+2)*8 + cgu];
      float4 w3 = whr[(c4*4+3)*8 + cgu];
      a0 += xv.x*w0.x + xv.y*w1.x + xv.z*w2.x + xv.w*w3.x;
      a1 += xv.x*w0.y + xv.y*w1.y + xv.z*w2.y + xv.w*w3.y;
      a2 += xv.x*w0.z + xv.y*w1.z + xv.z*w2.z + xv.w*w3.z;
      a3 += xv.x*w0.w + xv.y*w1.w + xv.z*w2.w + xv.w*w3.w;
    }
    float4 bv = ((const float4*)bh)[cgu];
    ushort4 hb = { f2bf(a0+bv.x), f2bf(a1+bv.y), f2bf(a2+bv.z), f2bf(a3+bv.w) };
    *(ushort4*)&hOut[(size_t)(r0+row)*32 + cgu*4] = hb;
  }
}

// ---------------- Kernel B: quarter-octave radix-select + slist + 4-wave exact final --
// 2048 blocks; block: 16 queries, 4 waves each scanning a 1024-pt quarter.
// Pass 1 (full sample): MFMA d^2 -> 128 quarter-octave bins (u>>21, window exp[110,142)).
// Prefix -> tau = end of the bin holding the 16th smallest (tight: ~25-60 survivors).
// Pass 2: push survivor indices (u < tau) to slist; scnt counts ALL (overflow-> fallback).
// Final (ALL 4 waves, stride 16): exact fp32 d^2 -> bubble -> in-wave + cross-wave merge.
#define BUBBLE16(v)                                              \
  { _Pragma("unroll")                                            \
    for (int k=0;k<16;++k){                                      \
      unsigned int mn = (v) < bp[k] ? (v) : bp[k];               \
      unsigned int mx = (v) < bp[k] ? bp[k] : (v);               \
      bp[k] = mn; (v) = mx;                                      \
    } }

#define MERGE16(OT)                                              \
  { unsigned int c[16];                                          \
    _Pragma("unroll")                                            \
    for (int k=0;k<16;++k){ unsigned int b2 = (OT)[15-k];        \
      c[k] = bp[k] < b2 ? bp[k] : b2; }                          \
    _Pragma("unroll")                                            \
    for (int d=8; d>=1; d>>=1){                                  \
      _Pragma("unroll")                                          \
      for (int i=0;i<16;++i){                                    \
        if ((i & d) == 0){                                       \
          unsigned int lo = c[i] < c[i+d] ? c[i] : c[i+d];       \
          unsigned int hi = c[i] < c[i+d] ? c[i+d] : c[i];       \
          c[i] = lo; c[i+d] = hi;                                \
        }                                                        \
      }                                                          \
    }                                                            \
    _Pragma("unroll")                                            \
    for (int k=0;k<16;++k) bp[k] = c[k]; }

#define SCAP 512
#define BIN_LO 440u   // 110*4: window start (exp 110 -> d2 ~ 4e-6)

__global__ __launch_bounds__(256, 8) void kB(
    const float* __restrict__ sIn, const uint4* __restrict__ sfrag,
    const unsigned short* __restrict__ hIn, unsigned short* __restrict__ Umini)
{
  __shared__ unsigned int hist[16*129];    // per-query 128 quarter-octave bins, stride 129
  __shared__ u16 slist[16*SCAP];           // per-query survivor indices
  __shared__ unsigned int scnt[16];
  __shared__ unsigned int tauL[16];
  __shared__ unsigned int mrg[48][17];     // cross-wave merge lists (waves 1-3)
  const int t = threadIdx.x;
  const int wv = t >> 6, l = t & 63;
  const int e = blockIdx.x >> 8;           // 256 blocks/event
  const int qblk = (blockIdx.x & 255) * 16;
  const int q16 = l & 15, g = l >> 4;
  const int qloc = qblk + q16;

  const float4* sg = (const float4*)sIn;
  const float4 sq = sg[(size_t)e*EV + qloc];
  const float si2 = sq.x*sq.x + sq.y*sq.y + sq.z*sq.z + sq.w*sq.w;

  // B (query) fragment: g0: [-2s hi4 | -2s lo4]; g1: [-2s hi4 | 1, 1, si2h, si2l]
  union BU { u16 u[8]; short8 v; } bu;
  #pragma unroll
  for (int i2=0;i2<8;++i2) bu.u[i2]=0;
  {
    float tx=-2.f*sq.x, ty=-2.f*sq.y, tz=-2.f*sq.z, tw=-2.f*sq.w;
    u16 h0=f2bf(tx), h1=f2bf(ty), h2=f2bf(tz), h3=f2bf(tw);
    if (g==0){
      float e0 = tx - __uint_as_float((unsigned)h0<<16);
      float e1 = ty - __uint_as_float((unsigned)h1<<16);
      float e2 = tz - __uint_as_float((unsigned)h2<<16);
      float e3 = tw - __uint_as_float((unsigned)h3<<16);
      bu.u[0]=h0; bu.u[1]=h1; bu.u[2]=h2; bu.u[3]=h3;
      bu.u[4]=f2bf(e0); bu.u[5]=f2bf(e1); bu.u[6]=f2bf(e2); bu.u[7]=f2bf(e3);
    } else if (g==1){
      u16 sh = f2bf(si2);
      u16 sl = f2bf(si2 - __uint_as_float((unsigned)sh<<16));
      bu.u[0]=h0; bu.u[1]=h1; bu.u[2]=h2; bu.u[3]=h3;
      bu.u[4]=0x3F80; bu.u[5]=0x3F80; bu.u[6]=sh; bu.u[7]=sl;
    }
  }
  const short8 bq = bu.v;

  // zero histogram + counters
  for (int i=t; i<16*129; i+=256) hist[i]=0;
  if (t < 16) scnt[t] = 0;
  __syncthreads();

  const f32x4 zacc = {0.f,0.f,0.f,0.f};
  const uint4 zf4 = {0,0,0,0};
  const uint4* fw = sfrag + (((size_t)e*EV + wv*1024) << 1);
  const int a32 = q16*2 + g;               // lanes 0-31 load the 2 uint4 halves of point q16
  const bool ld = (l < 32);
  const int hbase = q16*129;

  // ---- pass 1: quarter-octave histogram over this wave's full 1024-pt quarter ----
  {
    uint4 f0 = ld ? fw[a32]      : zf4;
    uint4 f1 = ld ? fw[32 + a32] : zf4;
    uint4 f2 = ld ? fw[64 + a32] : zf4;
    for (int tl=0; tl<64; ++tl){
      uint4 fn = zf4;
      if (ld && tl+3 < 64) fn = fw[(size_t)(tl+3)*32 + a32];
      union { uint4 q; short8 v; } au; au.q = f0;
      f32x4 acc = __builtin_amdgcn_mfma_f32_16x16x32_bf16(au.v, bq, zacc, 0,0,0);
      f0 = f1; f1 = f2; f2 = fn;
      unsigned b4[4];
      #pragma unroll
      for (int rg=0; rg<4; ++rg){
        unsigned u = __float_as_uint(fmaxf(acc[rg],0.f));
        unsigned q21 = u >> 21;
        b4[rg] = (q21 < BIN_LO) ? 0u : umin_(q21 - BIN_LO, 127u);
      }
      // in-lane first-occurrence combine: 1-4 atomics instead of 4
      unsigned a0 = 1u + (b4[1]==b4[0]) + (b4[2]==b4[0]) + (b4[3]==b4[0]);
      bool f1o = (b4[1]!=b4[0]);
      bool f2o = (b4[2]!=b4[0]) && (b4[2]!=b4[1]);
      bool f3o = (b4[3]!=b4[0]) && (b4[3]!=b4[1]) && (b4[3]!=b4[2]);
      unsigned a1 = 1u + (b4[2]==b4[1]) + (b4[3]==b4[1]);
      unsigned a2 = 1u + (b4[3]==b4[2]);
      atomicAdd(&hist[hbase + b4[0]], a0);
      if (f1o) atomicAdd(&hist[hbase + b4[1]], a1);
      if (f2o) atomicAdd(&hist[hbase + b4[2]], a2);
      if (f3o) atomicAdd(&hist[hbase + b4[3]], 1u);
    }
  }
  __syncthreads();

  // ---- prefix: find tau per query (16 threads per query, chunks of 8 bins) ----
  {
    int q = t >> 4, i = t & 15;
    int base = q*129 + i*8;
    unsigned cs = 0;
    #pragma unroll
    for (int k2=0;k2<8;++k2) cs += hist[base+k2];
    unsigned ps = cs;
    #pragma unroll
    for (int d=1; d<16; d<<=1){
      unsigned o = __shfl_up(ps, d, 16);
      if ((t&15) >= d) ps += o;
    }
    if (ps >= 16u && (ps - cs) < 16u){
      unsigned run = ps - cs;
      unsigned B = 127;
      #pragma unroll
      for (int k2=0;k2<8;++k2){
        unsigned c2 = hist[base+k2];
        bool hit = (run < 16u) && (run + c2 >= 16u);
        if (hit) B = (unsigned)(i*8 + k2);
        run += c2;
      }
      // bin 127 is open-ended (clamped): cannot bound its members -> force fallback
      tauL[q] = (B >= 127u) ? 0x7F800001u : ((BIN_LO + B + 1u) << 21);
    }
  }
  __syncthreads();
  const unsigned tauB = tauL[q16];

  // ---- pass 2: full quarter scan, push survivor indices (scnt counts ALL) ----
  {
    uint4 f0 = ld ? fw[a32]      : zf4;
    uint4 f1 = ld ? fw[32 + a32] : zf4;
    uint4 f2 = ld ? fw[64 + a32] : zf4;
    int jt = wv*1024 + g*4;
    for (int tl=0; tl<64; ++tl){
      uint4 fn = zf4;
      if (ld && tl+3 < 64) fn = fw[(size_t)(tl+3)*32 + a32];
      union { uint4 q; short8 v; } au; au.q = f0;
      f32x4 acc = __builtin_amdgcn_mfma_f32_16x16x32_bf16(au.v, bq, zacc, 0,0,0);
      f0 = f1; f1 = f2; f2 = fn;
      #pragma unroll
      for (int rg=0; rg<4; ++rg){
        unsigned u = __float_as_uint(fmaxf(acc[rg],0.f));
        if (u < tauB){
          unsigned idx = atomicAdd(&scnt[q16], 1u);
          if (idx < (unsigned)SCAP) slist[q16*SCAP + idx] = (u16)(jt + rg);
        }
      }
      jt += 16;
    }
  }
  __syncthreads();

  // ---- final: exact fp32 d^2 -> top-16; ALL 4 waves share the work (stride 16) ----
  unsigned scn_raw = scnt[q16];
  unsigned int bp[16];
  #pragma unroll
  for (int k=0;k<16;++k) bp[k]=0xFFFFFFFFu;
  const int lane16 = wv*4 + g;             // 0..15 within each query's 16 helper lanes
  if (scn_raw > (unsigned)SCAP){
    // overflow fallback: exact scan of all EV points (correctness guarantee, cold)
    for (int jj=lane16; jj<EV; jj+=16){
      float4 s4 = sg[(size_t)e*EV + jj];
      float dx = sq.x-s4.x, dy = sq.y-s4.y, dz = sq.z-s4.z, dw = sq.w-s4.w;
      float d2 = dx*dx + dy*dy + dz*dz + dw*dw;
      unsigned key = (__float_as_uint(d2) & 0xFFFFF000u) | (unsigned)jj;
      if (key < bp[15]) { BUBBLE16(key) }
    }
  } else {
    for (unsigned i=lane16; i<scn_raw; i+=16){
      int jj = (int)slist[q16*SCAP + i];
      float4 s4 = sg[(size_t)e*EV + jj];
      float dx = sq.x-s4.x, dy = sq.y-s4.y, dz = sq.z-s4.z, dw = sq.w-s4.w;
      float d2 = dx*dx + dy*dy + dz*dz + dw*dw;
      unsigned key = (__float_as_uint(d2) & 0xFFFFF000u) | (unsigned)jj;
      BUBBLE16(key)
    }
  }

  // in-wave merge across the 4 rowgrp-lanes of each query (xor 16, then xor 32)
  #pragma unroll
  for (int st=0; st<2; ++st){
    const int msk = (st==0) ? 16 : 32;
    unsigned int ot[16];
    #pragma unroll
    for (int k=0;k<16;++k) ot[k] = (unsigned int)__shfl_xor((int)bp[k], msk, 64);
    MERGE16(ot)
  }

  // cross-wave merge: waves 1-3 publish, wave 0 merges + aggregates
  if (wv != 0 && l < 16){
    #pragma unroll
    for (int k=0;k<16;++k) mrg[(wv-1)*16 + l][k] = bp[k];
  }
  __syncthreads();
  if (wv != 0) return;
  #pragma unroll
  for (int w=0; w<3; ++w){
    unsigned int ot[16];
    #pragma unroll
    for (int k=0;k<16;++k) ot[k] = mrg[w*16 + q16][k];
    MERGE16(ot)
  }

  // aggregation: lane (q16, g) owns features g*8..g*8+7 for all 16 neighbors
  float am[8], ax[8];
  #pragma unroll
  for (int p=0;p<8;++p){ am[p]=0.f; ax[p]=-3.4e38f; }
  const uint4* hb = (const uint4*)(hIn + (size_t)e*EV*32);
  #pragma unroll
  for (int i=0;i<16;++i){
    unsigned int key = bp[i];
    int j = (int)(key & 0xFFFu);
    float d2 = __uint_as_float(key & 0xFFFFF000u);
    float w = __expf(-10.f * d2);
    uint4 hv = hb[(size_t)j*4 + g];
    unsigned int uu[4] = {hv.x, hv.y, hv.z, hv.w};
    #pragma unroll
    for (int c2=0;c2<4;++c2){
      float flo = __uint_as_float(uu[c2] << 16);
      float fhi = __uint_as_float(uu[c2] & 0xFFFF0000u);
      float m0 = w*flo, m1 = w*fhi;
      am[c2*2]   += m0;                 am[c2*2+1] += m1;
      ax[c2*2]    = fmaxf(ax[c2*2],m0); ax[c2*2+1]  = fmaxf(ax[c2*2+1],m1);
    }
  }
  {
    unsigned short* Ur = Umini + ((size_t)e*EV + qloc)*64;
    uint4 pm, px;
    pm.x = (unsigned)f2bf(am[0]*(1.f/16.f)) | ((unsigned)f2bf(am[1]*(1.f/16.f))<<16);
    pm.y = (unsigned)f2bf(am[2]*(1.f/16.f)) | ((unsigned)f2bf(am[3]*(1.f/16.f))<<16);
    pm.z = (unsigned)f2bf(am[4]*(1.f/16.f)) | ((unsigned)f2bf(am[5]*(1.f/16.f))<<16);
    pm.w = (unsigned)f2bf(am[6]*(1.f/16.f)) | ((unsigned)f2bf(am[7]*(1.f/16.f))<<16);
    px.x = (unsigned)f2bf(ax[0]) | ((unsigned)f2bf(ax[1])<<16);
    px.y = (unsigned)f2bf(ax[2]) | ((unsigned)f2bf(ax[3])<<16);
    px.z = (unsigned)f2bf(ax[4]) | ((unsigned)f2bf(ax[5])<<16);
    px.w = (unsigned)f2bf(ax[6]) | ((unsigned)f2bf(ax[7])<<16);
    *(uint4*)(Ur +  0 + g*8) = pm;
    *(uint4*)(Ur + 32 + g*8) = px;
  }
}

// ---------------- Kernel C: x_new = [bf16(x)|Umini] @ Wo + bo ; residual ; LayerNorm ----
__global__ __launch_bounds__(256, 4) void kC(
    const unsigned short* __restrict__ Umini, const unsigned short* __restrict__ WoT,
    const float* __restrict__ bo, const float* __restrict__ x,
    const float* __restrict__ gamma, const float* __restrict__ beta,
    float* __restrict__ out)
{
  __shared__ unsigned short At[64*40];    // [64 rows][32k padded to 40]
  __shared__ unsigned short Bt[256*40];   // [256 cols][32k padded to 40]
  __shared__ float ps[64*4], pq[64*4];
  const int t = threadIdx.x;
  const int r0 = blockIdx.x * 64;
  const int l = t & 63, wv = t >> 6;
  const int lq = l & 15, g = l >> 4;
  f32x4 acc[4][4];
  const f32x4 zero = {0.f,0.f,0.f,0.f};
  #pragma unroll
  for (int m=0;m<4;++m)
    #pragma unroll
    for (int n=0;n<4;++n) acc[m][n] = zero;

  for (int kk=0; kk<10; ++kk){
    const int k0 = kk*32;
    __syncthreads();
    { // stage A: k<256 from x (fp32 -> bf16 via v_cvt_pk), else from Umini
      int row = t >> 2, ko = (t & 3)*8;
      uint4 av;
      if (k0 < 256){
        const float4* xr = (const float4*)(x + (size_t)(r0+row)*256 + k0 + ko);
        float4 u0 = xr[0], u1 = xr[1];
        unsigned p0,p1,p2,p3;
        asm("v_cvt_pk_bf16_f32 %0, %1, %2" : "=v"(p0) : "v"(u0.x), "v"(u0.y));
        asm("v_cvt_pk_bf16_f32 %0, %1, %2" : "=v"(p1) : "v"(u0.z), "v"(u0.w));
        asm("v_cvt_pk_bf16_f32 %0, %1, %2" : "=v"(p2) : "v"(u1.x), "v"(u1.y));
        asm("v_cvt_pk_bf16_f32 %0, %1, %2" : "=v"(p3) : "v"(u1.z), "v"(u1.w));
        av.x = p0; av.y = p1; av.z = p2; av.w = p3;
      } else {
        av = *(const uint4*)(Umini + (size_t)(r0+row)*64 + (k0-256) + ko);
      }
      *(uint4*)(At + row*40 + ko) = av;
    }
    { // stage B^T from pre-transposed WoT [256 cols][320 k] bf16
      int col = t;
      const uint4* src = (const uint4*)(WoT + (size_t)col*320 + k0);
      #pragma unroll
      for (int j=0;j<4;++j) *(uint4*)(Bt + col*40 + j*8) = src[j];
    }
    __syncthreads();
    short8 a[4], b[4];
    #pragma unroll
    for (int m=0;m<4;++m) a[m] = *(const short8*)(At + (16*m+lq)*40 + g*8);
    #pragma unroll
    for (int n=0;n<4;++n) b[n] = *(const short8*)(Bt + (wv*64 + 16*n + lq)*40 + g*8);
    #pragma unroll
    for (int m=0;m<4;++m)
      #pragma unroll
      for (int n=0;n<4;++n)
        acc[m][n] = __builtin_amdgcn_mfma_f32_16x16x32_bf16(a[m], b[n], acc[m][n], 0, 0, 0);
  }

  // epilogue: + bo + x(residual), LayerNorm over 256 cols
  float bo_n[4], ga_n[4], be_n[4];
  #pragma unroll
  for (int n=0;n<4;++n){
    int colg = wv*64 + 16*n + lq;
    bo_n[n] = bo[colg]; ga_n[n] = gamma[colg]; be_n[n] = beta[colg];
  }
  float pr[4][4], pr2[4][4];
  #pragma unroll
  for (int m=0;m<4;++m){
    #pragma unroll
    for (int rg=0;rg<4;++rg){
      int rowg = r0 + 16*m + g*4 + rg;
      float sum=0.f, sq=0.f;
      #pragma unroll
      for (int n=0;n<4;++n){
        int colg = wv*64 + 16*n + lq;
        float y = acc[m][n][rg] + bo_n[n] + x[(size_t)rowg*256 + colg];
        acc[m][n][rg] = y;
        sum += y; sq += y*y;
      }
      sum += __shfl_xor(sum,1); sq += __shfl_xor(sq,1);
      sum += __shfl_xor(sum,2); sq += __shfl_xor(sq,2);
      sum += __shfl_xor(sum,4); sq += __shfl_xor(sq,4);
      sum += __shfl_xor(sum,8); sq += __shfl_xor(sq,8);
      pr[m][rg]=sum; pr2[m][rg]=sq;
    }
  }
  if (lq == 0){
    #pragma unroll
    for (int m=0;m<4;++m)
      #pragma unroll
      for (int rg=0;rg<4;++rg){
        int rowl = 16*m + g*4 + rg;
        ps[rowl*4 + wv] = pr[m][rg];
        pq[rowl*4 + wv] = pr2[m][rg];
      }
  }
  __syncthreads();
  #pragma unroll
  for (int m=0;m<4;++m){
    #pragma unroll
    for (int rg=0;rg<4;++rg){
      int rowl = 16*m + g*4 + rg;
      float sum = ps[rowl*4+0]+ps[rowl*4+1]+ps[rowl*4+2]+ps[rowl*4+3];
      float sq  = pq[rowl*4+0]+pq[rowl*4+1]+pq[rowl*4+2]+pq[rowl*4+3];
      float mu  = sum * (1.f/256.f);
      float var = sq * (1.f/256.f) - mu*mu;
      float inv = rsqrtf(var + 1e-5f);
      int rowg = r0 + rowl;
      #pragma unroll
      for (int n=0;n<4;++n){
        int colg = wv*64 + 16*n + lq;
        out[(size_t)rowg*256 + colg] = ga_n[n]*(acc[m][n][rg] - mu)*inv + be_n[n];
      }
    }
  }
}

extern "C" void kernel_launch(void* const* d_in, const int* in_sizes, int n_in,
                              void* d_out, int out_size, void* d_ws, size_t ws_size,
                              hipStream_t stream)
{
  const float* x     = (const float*)d_in[0];
  // d_in[1] = batch_index (block-sorted equal events; unused)
  const float* Ws    = (const float*)d_in[2];
  const float* bs    = (const float*)d_in[3];
  const float* Wh    = (const float*)d_in[4];
  const float* bh    = (const float*)d_in[5];
  const float* Wo    = (const float*)d_in[6];
  const float* bo    = (const float*)d_in[7];
  const float* gamma = (const float*)d_in[8];
  const float* beta  = (const float*)d_in[9];
  float* out = (float*)d_out;

  char* ws = (char*)d_ws;
  float*          sBuf  = (float*)ws;                        // N*4 f32    = 0.5 MB
  uint4*          sfrag = (uint4*)(ws + 524288);             // N*32 B     = 1 MB
  unsigned short* hBuf  = (unsigned short*)(ws + 1572864);   // N*32 bf16  = 2 MB
  unsigned short* Umini = (unsigned short*)(ws + 3670016);   // N*64 bf16  = 4 MB
  unsigned short* WoT   = (unsigned short*)(ws + 7864320);   // 256*320 bf16 = 160 KB

  kA<<<dim3(N_TOT/64 + 10), dim3(256), 0, stream>>>(x, Ws, bs, Wh, bh, Wo,
                                                    sBuf, sfrag, hBuf, (unsigned int*)WoT);
  kB<<<dim3(N_TOT/16), dim3(256), 0, stream>>>(sBuf, sfrag, hBuf, Umini);
  kC<<<dim3(N_TOT/64), dim3(256), 0, stream>>>(Umini, WoT, bo, x, gamma, beta, out);
}

// Round 10
// 196.770 us; speedup vs baseline: 1.9342x; 1.2525x over previous
//
#include <hip/hip_runtime.h>
#include <stdint.h>

typedef short short8 __attribute__((ext_vector_type(8)));
typedef float f32x4 __attribute__((ext_vector_type(4)));
typedef unsigned short u16;

#define N_TOT 32768
#define EV 4096

__device__ __forceinline__ u16 f2bf(float f){
  unsigned int x = __float_as_uint(f);
  x += 0x7FFFu + ((x >> 16) & 1u);
  return (u16)(x >> 16);
}
__device__ __forceinline__ unsigned umin_(unsigned a, unsigned b){ return a<b?a:b; }

// ---------------- Kernel A: s (fp32 + MFMA point-fragments), h (bf16); +kW fold ------
__global__ __launch_bounds__(256, 2) void kA(
    const float* __restrict__ x, const float* __restrict__ Ws,
    const float* __restrict__ bs, const float* __restrict__ Wh,
    const float* __restrict__ bh, const float* __restrict__ Wo,
    float* __restrict__ sOut, uint4* __restrict__ sfrag,
    unsigned short* __restrict__ hOut, unsigned int* __restrict__ WoT2)
{
  if (blockIdx.x >= N_TOT/64){                 // folded kW: Wo [320][256] f32 -> WoT [256][320] bf16
    const int kb = (blockIdx.x - N_TOT/64) * 32;
    const int c = threadIdx.x;
    unsigned int prev = 0;
    for (int k=0;k<32;++k){
      float v = Wo[(size_t)(kb+k)*256 + c];
      u16 h = f2bf(v);
      if (k & 1) WoT2[(size_t)c*160 + ((kb+k)>>1)] = prev | ((unsigned)h<<16);
      else       prev = (unsigned)h;
    }
    return;
  }
  __shared__ float xs[64*256];   // 64 rows, float4-chunk XOR swizzle
  const int t = threadIdx.x;
  const int r0 = blockIdx.x * 64;
  const float4* xg = (const float4*)(x + (size_t)r0*256);
  #pragma unroll
  for (int i=0;i<16;++i){
    int f = t + 256*i;
    int row = f >> 6, c4 = f & 63;
    float4 v = xg[f];
    *(float4*)&xs[row*256 + (c4 ^ (row&7))*4] = v;
  }
  __syncthreads();
  // s: fp32. thread: row = t>>2, k-quarter = t&3 ; reduce across k-quarters via shfl.
  {
    int row = t >> 2, kq = t & 3;
    float a0=0.f,a1=0.f,a2=0.f,a3=0.f;
    const float4* wsr = (const float4*)Ws;   // Ws[k][0..3]
    #pragma unroll 4
    for (int i=0;i<16;++i){
      int c4 = kq*16 + i;
      float4 xv = *(const float4*)&xs[row*256 + (c4 ^ (row&7))*4];
      float4 w0 = wsr[c4*4+0], w1 = wsr[c4*4+1], w2 = wsr[c4*4+2], w3 = wsr[c4*4+3];
      a0 += xv.x*w0.x + xv.y*w1.x + xv.z*w2.x + xv.w*w3.x;
      a1 += xv.x*w0.y + xv.y*w1.y + xv.z*w2.y + xv.w*w3.y;
      a2 += xv.x*w0.z + xv.y*w1.z + xv.z*w2.z + xv.w*w3.z;
      a3 += xv.x*w0.w + xv.y*w1.w + xv.z*w2.w + xv.w*w3.w;
    }
    a0 += __shfl_xor(a0,1); a0 += __shfl_xor(a0,2);
    a1 += __shfl_xor(a1,1); a1 += __shfl_xor(a1,2);
    a2 += __shfl_xor(a2,1); a2 += __shfl_xor(a2,2);
    a3 += __shfl_xor(a3,1); a3 += __shfl_xor(a3,2);
    if (kq == 0){
      float4 sv = { a0+bs[0], a1+bs[1], a2+bs[2], a3+bs[3] };
      ((float4*)sOut)[r0 + row] = sv;
      // A-side (point) fragment: k0-7 = [hi4,hi4]; k8-15 = [lo4, nh, nl, 1, 1]
      u16 h0=f2bf(sv.x), h1=f2bf(sv.y), h2=f2bf(sv.z), h3=f2bf(sv.w);
      float e0 = sv.x - __uint_as_float((unsigned)h0<<16);
      float e1 = sv.y - __uint_as_float((unsigned)h1<<16);
      float e2 = sv.z - __uint_as_float((unsigned)h2<<16);
      float e3 = sv.w - __uint_as_float((unsigned)h3<<16);
      u16 l0=f2bf(e0), l1=f2bf(e1), l2=f2bf(e2), l3=f2bf(e3);
      float n = sv.x*sv.x + sv.y*sv.y + sv.z*sv.z + sv.w*sv.w;
      u16 nh = f2bf(n);
      u16 nl = f2bf(n - __uint_as_float((unsigned)nh<<16));
      uint4 w0, w1;
      w0.x = (unsigned)h0 | ((unsigned)h1<<16);
      w0.y = (unsigned)h2 | ((unsigned)h3<<16);
      w0.z = w0.x; w0.w = w0.y;
      w1.x = (unsigned)l0 | ((unsigned)l1<<16);
      w1.y = (unsigned)l2 | ((unsigned)l3<<16);
      w1.z = (unsigned)nh | ((unsigned)nl<<16);
      w1.w = 0x3F803F80u;                       // 1.0, 1.0 (pairs with B's si2 hi/lo)
      sfrag[(size_t)(r0+row)*2 + 0] = w0;
      sfrag[(size_t)(r0+row)*2 + 1] = w1;
    }
  }
  // h: row = t&63, col-group (4 cols) = wave + 4*rd
  const float4* whr = (const float4*)Wh;   // Wh[k][32]
  #pragma unroll
  for (int rd=0; rd<2; ++rd){
    int row = t & 63;
    int cg = (t >> 6) + rd*4;
    int cgu = __builtin_amdgcn_readfirstlane(cg);
    float a0=0.f,a1=0.f,a2=0.f,a3=0.f;
    #pragma unroll 4
    for (int c4=0;c4<64;++c4){
      float4 xv = *(const float4*)&xs[row*256 + (c4 ^ (row&7))*4];
      float4 w0 = whr[(c4*4+0)*8 + cgu];
      float4 w1 = whr[(c4*4+1)*8 + cgu];
      float4 w2 = whr[(c4*4+2)*8 + cgu];
      float4 w3 = whr[(c4*4+3)*8 + cgu];
      a0 += xv.x*w0.x + xv.y*w1.x + xv.z*w2.x + xv.w*w3.x;
      a1 += xv.x*w0.y + xv.y*w1.y + xv.z*w2.y + xv.w*w3.y;
      a2 += xv.x*w0.z + xv.y*w1.z + xv.z*w2.z + xv.w*w3.z;
      a3 += xv.x*w0.w + xv.y*w1.w + xv.z*w2.w + xv.w*w3.w;
    }
    float4 bv = ((const float4*)bh)[cgu];
    ushort4 hb = { f2bf(a0+bv.x), f2bf(a1+bv.y), f2bf(a2+bv.z), f2bf(a3+bv.w) };
    *(ushort4*)&hOut[(size_t)(r0+row)*32 + cgu*4] = hb;
  }
}

// ---------------- Kernel B: half-sample quarter-octave radix-select, lean scan loops --
// 2048 blocks; block: 16 queries, 4 waves each scanning a 1024-pt quarter.
// Pass 1 (32 tiles/wave = half sample): 128 quarter-octave bins (u>>21 window) -> tau.
//   Subset tau remains a valid upper bound on the true 16th-NN distance.
// Pass 2 (64 tiles/wave): push survivor indices (u < tau) to slist; scnt counts ALL.
// Final (ALL 4 waves, stride 16): exact fp32 d^2; overflow -> exact full-scan fallback.
// Scan loops: 4-deep prefetch ring, manually unrolled (no rotation movs, no bounds
// checks -- over-read of <=4 tiles lands in adjacent ws buffers, values unused).
#define BUBBLE16(v)                                              \
  { _Pragma("unroll")                                            \
    for (int k=0;k<16;++k){                                      \
      unsigned int mn = (v) < bp[k] ? (v) : bp[k];               \
      unsigned int mx = (v) < bp[k] ? bp[k] : (v);               \
      bp[k] = mn; (v) = mx;                                      \
    } }

#define MERGE16(OT)                                              \
  { unsigned int c[16];                                          \
    _Pragma("unroll")                                            \
    for (int k=0;k<16;++k){ unsigned int b2 = (OT)[15-k];        \
      c[k] = bp[k] < b2 ? bp[k] : b2; }                          \
    _Pragma("unroll")                                            \
    for (int d=8; d>=1; d>>=1){                                  \
      _Pragma("unroll")                                          \
      for (int i=0;i<16;++i){                                    \
        if ((i & d) == 0){                                       \
          unsigned int lo = c[i] < c[i+d] ? c[i] : c[i+d];       \
          unsigned int hi = c[i] < c[i+d] ? c[i+d] : c[i];       \
          c[i] = lo; c[i+d] = hi;                                \
        }                                                        \
      }                                                          \
    }                                                            \
    _Pragma("unroll")                                            \
    for (int k=0;k<16;++k) bp[k] = c[k]; }

#define SCAP 512
#define BIN_LO 440u   // 110*4: window start (exp 110 -> d2 ~ 4e-6)

// pass-1 body: MFMA, refill, histogram (plain atomics)
#define P1BODY(F, TL)                                            \
  { union { uint4 q; short8 v; } au; au.q = (F);                 \
    if (ld) (F) = fw[(size_t)((TL)+4)*32 + a32];                 \
    f32x4 acc = __builtin_amdgcn_mfma_f32_16x16x32_bf16(au.v, bq, zacc, 0,0,0); \
    _Pragma("unroll")                                            \
    for (int rg=0; rg<4; ++rg){                                  \
      unsigned u = __float_as_uint(fmaxf(acc[rg],0.f));          \
      unsigned q21 = u >> 21;                                    \
      unsigned b = (q21 < BIN_LO) ? 0u : umin_(q21 - BIN_LO, 127u); \
      atomicAdd(&hist[hbase + b], 1u);                           \
    } }

// pass-2 body: MFMA, refill, predicated survivor push
#define P2BODY(F, TL)                                            \
  { union { uint4 q; short8 v; } au; au.q = (F);                 \
    if (ld) (F) = fw[(size_t)((TL)+4)*32 + a32];                 \
    f32x4 acc = __builtin_amdgcn_mfma_f32_16x16x32_bf16(au.v, bq, zacc, 0,0,0); \
    const int jb = jt + (TL)*16;                                 \
    _Pragma("unroll")                                            \
    for (int rg=0; rg<4; ++rg){                                  \
      unsigned u = __float_as_uint(fmaxf(acc[rg],0.f));          \
      if (u < tauB){                                             \
        unsigned idx = atomicAdd(&scnt[q16], 1u);                \
        if (idx < (unsigned)SCAP) slist[q16*SCAP + idx] = (u16)(jb + rg); \
      }                                                          \
    } }

__global__ __launch_bounds__(256, 8) void kB(
    const float* __restrict__ sIn, const uint4* __restrict__ sfrag,
    const unsigned short* __restrict__ hIn, unsigned short* __restrict__ Umini)
{
  __shared__ unsigned int hist[16*129];    // per-query 128 quarter-octave bins, stride 129
  __shared__ u16 slist[16*SCAP];           // per-query survivor indices
  __shared__ unsigned int scnt[16];
  __shared__ unsigned int tauL[16];
  __shared__ unsigned int mrg[48][17];     // cross-wave merge lists (waves 1-3)
  const int t = threadIdx.x;
  const int wv = t >> 6, l = t & 63;
  const int e = blockIdx.x >> 8;           // 256 blocks/event
  const int qblk = (blockIdx.x & 255) * 16;
  const int q16 = l & 15, g = l >> 4;
  const int qloc = qblk + q16;

  const float4* sg = (const float4*)sIn;
  const float4 sq = sg[(size_t)e*EV + qloc];
  const float si2 = sq.x*sq.x + sq.y*sq.y + sq.z*sq.z + sq.w*sq.w;

  // B (query) fragment: g0: [-2s hi4 | -2s lo4]; g1: [-2s hi4 | 1, 1, si2h, si2l]
  union BU { u16 u[8]; short8 v; } bu;
  #pragma unroll
  for (int i2=0;i2<8;++i2) bu.u[i2]=0;
  {
    float tx=-2.f*sq.x, ty=-2.f*sq.y, tz=-2.f*sq.z, tw=-2.f*sq.w;
    u16 h0=f2bf(tx), h1=f2bf(ty), h2=f2bf(tz), h3=f2bf(tw);
    if (g==0){
      float e0 = tx - __uint_as_float((unsigned)h0<<16);
      float e1 = ty - __uint_as_float((unsigned)h1<<16);
      float e2 = tz - __uint_as_float((unsigned)h2<<16);
      float e3 = tw - __uint_as_float((unsigned)h3<<16);
      bu.u[0]=h0; bu.u[1]=h1; bu.u[2]=h2; bu.u[3]=h3;
      bu.u[4]=f2bf(e0); bu.u[5]=f2bf(e1); bu.u[6]=f2bf(e2); bu.u[7]=f2bf(e3);
    } else if (g==1){
      u16 sh = f2bf(si2);
      u16 sl = f2bf(si2 - __uint_as_float((unsigned)sh<<16));
      bu.u[0]=h0; bu.u[1]=h1; bu.u[2]=h2; bu.u[3]=h3;
      bu.u[4]=0x3F80; bu.u[5]=0x3F80; bu.u[6]=sh; bu.u[7]=sl;
    }
  }
  const short8 bq = bu.v;

  // zero histogram + counters
  for (int i=t; i<16*129; i+=256) hist[i]=0;
  if (t < 16) scnt[t] = 0;
  __syncthreads();

  const f32x4 zacc = {0.f,0.f,0.f,0.f};
  const uint4 zf4 = {0,0,0,0};
  const uint4* fw = sfrag + (((size_t)e*EV + wv*1024) << 1);
  const int a32 = q16*2 + g;               // lanes 0-31 load the 2 uint4 halves of point q16
  const bool ld = (l < 32);
  const int hbase = q16*129;

  // ---- pass 1: quarter-octave histogram over first 512 pts of the quarter ----
  {
    uint4 f0 = ld ? fw[a32]      : zf4;
    uint4 f1 = ld ? fw[32 + a32] : zf4;
    uint4 f2 = ld ? fw[64 + a32] : zf4;
    uint4 f3 = ld ? fw[96 + a32] : zf4;
    for (int tl=0; tl<32; tl+=4){
      P1BODY(f0, tl+0)
      P1BODY(f1, tl+1)
      P1BODY(f2, tl+2)
      P1BODY(f3, tl+3)
    }
  }
  __syncthreads();

  // ---- prefix: find tau per query (16 threads per query, chunks of 8 bins) ----
  {
    int q = t >> 4, i = t & 15;
    int base = q*129 + i*8;
    unsigned cs = 0;
    #pragma unroll
    for (int k2=0;k2<8;++k2) cs += hist[base+k2];
    unsigned ps = cs;
    #pragma unroll
    for (int d=1; d<16; d<<=1){
      unsigned o = __shfl_up(ps, d, 16);
      if ((t&15) >= d) ps += o;
    }
    if (ps >= 16u && (ps - cs) < 16u){
      unsigned run = ps - cs;
      unsigned B = 127;
      #pragma unroll
      for (int k2=0;k2<8;++k2){
        unsigned c2 = hist[base+k2];
        bool hit = (run < 16u) && (run + c2 >= 16u);
        if (hit) B = (unsigned)(i*8 + k2);
        run += c2;
      }
      // bin 127 is open-ended (clamped): cannot bound its members -> force fallback
      tauL[q] = (B >= 127u) ? 0x7F800001u : ((BIN_LO + B + 1u) << 21);
    }
  }
  __syncthreads();
  const unsigned tauB = tauL[q16];

  // ---- pass 2: full quarter scan, push survivor indices (scnt counts ALL) ----
  {
    uint4 f0 = ld ? fw[a32]      : zf4;
    uint4 f1 = ld ? fw[32 + a32] : zf4;
    uint4 f2 = ld ? fw[64 + a32] : zf4;
    uint4 f3 = ld ? fw[96 + a32] : zf4;
    const int jt = wv*1024 + g*4;
    for (int tl=0; tl<64; tl+=4){
      P2BODY(f0, tl+0)
      P2BODY(f1, tl+1)
      P2BODY(f2, tl+2)
      P2BODY(f3, tl+3)
    }
  }
  __syncthreads();

  // ---- final: exact fp32 d^2 -> top-16; ALL 4 waves share the work (stride 16) ----
  unsigned scn_raw = scnt[q16];
  unsigned int bp[16];
  #pragma unroll
  for (int k=0;k<16;++k) bp[k]=0xFFFFFFFFu;
  const int lane16 = wv*4 + g;             // 0..15 within each query's 16 helper lanes
  if (scn_raw > (unsigned)SCAP){
    // overflow fallback: exact scan of all EV points (correctness guarantee, cold)
    for (int jj=lane16; jj<EV; jj+=16){
      float4 s4 = sg[(size_t)e*EV + jj];
      float dx = sq.x-s4.x, dy = sq.y-s4.y, dz = sq.z-s4.z, dw = sq.w-s4.w;
      float d2 = dx*dx + dy*dy + dz*dz + dw*dw;
      unsigned key = (__float_as_uint(d2) & 0xFFFFF000u) | (unsigned)jj;
      if (key < bp[15]) { BUBBLE16(key) }
    }
  } else {
    for (unsigned i=lane16; i<scn_raw; i+=16){
      int jj = (int)slist[q16*SCAP + i];
      float4 s4 = sg[(size_t)e*EV + jj];
      float dx = sq.x-s4.x, dy = sq.y-s4.y, dz = sq.z-s4.z, dw = sq.w-s4.w;
      float d2 = dx*dx + dy*dy + dz*dz + dw*dw;
      unsigned key = (__float_as_uint(d2) & 0xFFFFF000u) | (unsigned)jj;
      BUBBLE16(key)
    }
  }

  // in-wave merge across the 4 rowgrp-lanes of each query (xor 16, then xor 32)
  #pragma unroll
  for (int st=0; st<2; ++st){
    const int msk = (st==0) ? 16 : 32;
    unsigned int ot[16];
    #pragma unroll
    for (int k=0;k<16;++k) ot[k] = (unsigned int)__shfl_xor((int)bp[k], msk, 64);
    MERGE16(ot)
  }

  // cross-wave merge: waves 1-3 publish, wave 0 merges + aggregates
  if (wv != 0 && l < 16){
    #pragma unroll
    for (int k=0;k<16;++k) mrg[(wv-1)*16 + l][k] = bp[k];
  }
  __syncthreads();
  if (wv != 0) return;
  #pragma unroll
  for (int w=0; w<3; ++w){
    unsigned int ot[16];
    #pragma unroll
    for (int k=0;k<16;++k) ot[k] = mrg[w*16 + q16][k];
    MERGE16(ot)
  }

  // aggregation: lane (q16, g) owns features g*8..g*8+7 for all 16 neighbors
  float am[8], ax[8];
  #pragma unroll
  for (int p=0;p<8;++p){ am[p]=0.f; ax[p]=-3.4e38f; }
  const uint4* hb = (const uint4*)(hIn + (size_t)e*EV*32);
  #pragma unroll
  for (int i=0;i<16;++i){
    unsigned int key = bp[i];
    int j = (int)(key & 0xFFFu);
    float d2 = __uint_as_float(key & 0xFFFFF000u);
    float w = __expf(-10.f * d2);
    uint4 hv = hb[(size_t)j*4 + g];
    unsigned int uu[4] = {hv.x, hv.y, hv.z, hv.w};
    #pragma unroll
    for (int c2=0;c2<4;++c2){
      float flo = __uint_as_float(uu[c2] << 16);
      float fhi = __uint_as_float(uu[c2] & 0xFFFF0000u);
      float m0 = w*flo, m1 = w*fhi;
      am[c2*2]   += m0;                 am[c2*2+1] += m1;
      ax[c2*2]    = fmaxf(ax[c2*2],m0); ax[c2*2+1]  = fmaxf(ax[c2*2+1],m1);
    }
  }
  {
    unsigned short* Ur = Umini + ((size_t)e*EV + qloc)*64;
    uint4 pm, px;
    pm.x = (unsigned)f2bf(am[0]*(1.f/16.f)) | ((unsigned)f2bf(am[1]*(1.f/16.f))<<16);
    pm.y = (unsigned)f2bf(am[2]*(1.f/16.f)) | ((unsigned)f2bf(am[3]*(1.f/16.f))<<16);
    pm.z = (unsigned)f2bf(am[4]*(1.f/16.f)) | ((unsigned)f2bf(am[5]*(1.f/16.f))<<16);
    pm.w = (unsigned)f2bf(am[6]*(1.f/16.f)) | ((unsigned)f2bf(am[7]*(1.f/16.f))<<16);
    px.x = (unsigned)f2bf(ax[0]) | ((unsigned)f2bf(ax[1])<<16);
    px.y = (unsigned)f2bf(ax[2]) | ((unsigned)f2bf(ax[3])<<16);
    px.z = (unsigned)f2bf(ax[4]) | ((unsigned)f2bf(ax[5])<<16);
    px.w = (unsigned)f2bf(ax[6]) | ((unsigned)f2bf(ax[7])<<16);
    *(uint4*)(Ur +  0 + g*8) = pm;
    *(uint4*)(Ur + 32 + g*8) = px;
  }
}

// ---------------- Kernel C: x_new = [bf16(x)|Umini] @ Wo + bo ; residual ; LayerNorm ----
__global__ __launch_bounds__(256, 4) void kC(
    const unsigned short* __restrict__ Umini, const unsigned short* __restrict__ WoT,
    const float* __restrict__ bo, const float* __restrict__ x,
    const float* __restrict__ gamma, const float* __restrict__ beta,
    float* __restrict__ out)
{
  __shared__ unsigned short At[64*40];    // [64 rows][32k padded to 40]
  __shared__ unsigned short Bt[256*40];   // [256 cols][32k padded to 40]
  __shared__ float ps[64*4], pq[64*4];
  const int t = threadIdx.x;
  const int r0 = blockIdx.x * 64;
  const int l = t & 63, wv = t >> 6;
  const int lq = l & 15, g = l >> 4;
  f32x4 acc[4][4];
  const f32x4 zero = {0.f,0.f,0.f,0.f};
  #pragma unroll
  for (int m=0;m<4;++m)
    #pragma unroll
    for (int n=0;n<4;++n) acc[m][n] = zero;

  for (int kk=0; kk<10; ++kk){
    const int k0 = kk*32;
    __syncthreads();
    { // stage A: k<256 from x (fp32 -> bf16 via v_cvt_pk), else from Umini
      int row = t >> 2, ko = (t & 3)*8;
      uint4 av;
      if (k0 < 256){
        const float4* xr = (const float4*)(x + (size_t)(r0+row)*256 + k0 + ko);
        float4 u0 = xr[0], u1 = xr[1];
        unsigned p0,p1,p2,p3;
        asm("v_cvt_pk_bf16_f32 %0, %1, %2" : "=v"(p0) : "v"(u0.x), "v"(u0.y));
        asm("v_cvt_pk_bf16_f32 %0, %1, %2" : "=v"(p1) : "v"(u0.z), "v"(u0.w));
        asm("v_cvt_pk_bf16_f32 %0, %1, %2" : "=v"(p2) : "v"(u1.x), "v"(u1.y));
        asm("v_cvt_pk_bf16_f32 %0, %1, %2" : "=v"(p3) : "v"(u1.z), "v"(u1.w));
        av.x = p0; av.y = p1; av.z = p2; av.w = p3;
      } else {
        av = *(const uint4*)(Umini + (size_t)(r0+row)*64 + (k0-256) + ko);
      }
      *(uint4*)(At + row*40 + ko) = av;
    }
    { // stage B^T from pre-transposed WoT [256 cols][320 k] bf16
      int col = t;
      const uint4* src = (const uint4*)(WoT + (size_t)col*320 + k0);
      #pragma unroll
      for (int j=0;j<4;++j) *(uint4*)(Bt + col*40 + j*8) = src[j];
    }
    __syncthreads();
    short8 a[4], b[4];
    #pragma unroll
    for (int m=0;m<4;++m) a[m] = *(const short8*)(At + (16*m+lq)*40 + g*8);
    #pragma unroll
    for (int n=0;n<4;++n) b[n] = *(const short8*)(Bt + (wv*64 + 16*n + lq)*40 + g*8);
    #pragma unroll
    for (int m=0;m<4;++m)
      #pragma unroll
      for (int n=0;n<4;++n)
        acc[m][n] = __builtin_amdgcn_mfma_f32_16x16x32_bf16(a[m], b[n], acc[m][n], 0, 0, 0);
  }

  // epilogue: + bo + x(residual), LayerNorm over 256 cols
  float bo_n[4], ga_n[4], be_n[4];
  #pragma unroll
  for (int n=0;n<4;++n){
    int colg = wv*64 + 16*n + lq;
    bo_n[n] = bo[colg]; ga_n[n] = gamma[colg]; be_n[n] = beta[colg];
  }
  float pr[4][4], pr2[4][4];
  #pragma unroll
  for (int m=0;m<4;++m){
    #pragma unroll
    for (int rg=0;rg<4;++rg){
      int rowg = r0 + 16*m + g*4 + rg;
      float sum=0.f, sq=0.f;
      #pragma unroll
      for (int n=0;n<4;++n){
        int colg = wv*64 + 16*n + lq;
        float y = acc[m][n][rg] + bo_n[n] + x[(size_t)rowg*256 + colg];
        acc[m][n][rg] = y;
        sum += y; sq += y*y;
      }
      sum += __shfl_xor(sum,1); sq += __shfl_xor(sq,1);
      sum += __shfl_xor(sum,2); sq += __shfl_xor(sq,2);
      sum += __shfl_xor(sum,4); sq += __shfl_xor(sq,4);
      sum += __shfl_xor(sum,8); sq += __shfl_xor(sq,8);
      pr[m][rg]=sum; pr2[m][rg]=sq;
    }
  }
  if (lq == 0){
    #pragma unroll
    for (int m=0;m<4;++m)
      #pragma unroll
      for (int rg=0;rg<4;++rg){
        int rowl = 16*m + g*4 + rg;
        ps[rowl*4 + wv] = pr[m][rg];
        pq[rowl*4 + wv] = pr2[m][rg];
      }
  }
  __syncthreads();
  #pragma unroll
  for (int m=0;m<4;++m){
    #pragma unroll
    for (int rg=0;rg<4;++rg){
      int rowl = 16*m + g*4 + rg;
      float sum = ps[rowl*4+0]+ps[rowl*4+1]+ps[rowl*4+2]+ps[rowl*4+3];
      float sq  = pq[rowl*4+0]+pq[rowl*4+1]+pq[rowl*4+2]+pq[rowl*4+3];
      float mu  = sum * (1.f/256.f);
      float var = sq * (1.f/256.f) - mu*mu;
      float inv = rsqrtf(var + 1e-5f);
      int rowg = r0 + rowl;
      #pragma unroll
      for (int n=0;n<4;++n){
        int colg = wv*64 + 16*n + lq;
        out[(size_t)rowg*256 + colg] = ga_n[n]*(acc[m][n][rg] - mu)*inv + be_n[n];
      }
    }
  }
}

extern "C" void kernel_launch(void* const* d_in, const int* in_sizes, int n_in,
                              void* d_out, int out_size, void* d_ws, size_t ws_size,
                              hipStream_t stream)
{
  const float* x     = (const float*)d_in[0];
  // d_in[1] = batch_index (block-sorted equal events; unused)
  const float* Ws    = (const float*)d_in[2];
  const float* bs    = (const float*)d_in[3];
  const float* Wh    = (const float*)d_in[4];
  const float* bh    = (const float*)d_in[5];
  const float* Wo    = (const float*)d_in[6];
  const float* bo    = (const float*)d_in[7];
  const float* gamma = (const float*)d_in[8];
  const float* beta  = (const float*)d_in[9];
  float* out = (float*)d_out;

  char* ws = (char*)d_ws;
  float*          sBuf  = (float*)ws;                        // N*4 f32    = 0.5 MB
  uint4*          sfrag = (uint4*)(ws + 524288);             // N*32 B     = 1 MB
  unsigned short* hBuf  = (unsigned short*)(ws + 1572864);   // N*32 bf16  = 2 MB
  unsigned short* Umini = (unsigned short*)(ws + 3670016);   // N*64 bf16  = 4 MB
  unsigned short* WoT   = (unsigned short*)(ws + 7864320);   // 256*320 bf16 = 160 KB

  kA<<<dim3(N_TOT/64 + 10), dim3(256), 0, stream>>>(x, Ws, bs, Wh, bh, Wo,
                                                    sBuf, sfrag, hBuf, (unsigned int*)WoT);
  kB<<<dim3(N_TOT/16), dim3(256), 0, stream>>>(sBuf, sfrag, hBuf, Umini);
  kC<<<dim3(N_TOT/64), dim3(256), 0, stream>>>(Umini, WoT, bo, x, gamma, beta, out);
}

// Round 11
// 148.620 us; speedup vs baseline: 2.5608x; 1.3240x over previous
//
#include <hip/hip_runtime.h>
#include <stdint.h>

typedef short short8 __attribute__((ext_vector_type(8)));
typedef float f32x4 __attribute__((ext_vector_type(4)));
typedef unsigned short u16;

#define N_TOT 32768
#define EV 4096

__device__ __forceinline__ u16 f2bf(float f){
  unsigned int x = __float_as_uint(f);
  x += 0x7FFFu + ((x >> 16) & 1u);
  return (u16)(x >> 16);
}
__device__ __forceinline__ unsigned umin_(unsigned a, unsigned b){ return a<b?a:b; }

// ---------------- Kernel A: s (fp32, global reads), h (bf16 MFMA), sfrag; +kW fold ---
__global__ __launch_bounds__(256, 3) void kA(
    const float* __restrict__ x, const float* __restrict__ Ws,
    const float* __restrict__ bs, const float* __restrict__ Wh,
    const float* __restrict__ bh, const float* __restrict__ Wo,
    float* __restrict__ sOut, uint4* __restrict__ sfrag,
    unsigned short* __restrict__ hOut, unsigned int* __restrict__ WoT2)
{
  if (blockIdx.x >= N_TOT/64){                 // folded kW: Wo [320][256] f32 -> WoT [256][320] bf16
    const int kb = (blockIdx.x - N_TOT/64) * 32;
    const int c = threadIdx.x;
    unsigned int prev = 0;
    for (int k=0;k<32;++k){
      float v = Wo[(size_t)(kb+k)*256 + c];
      u16 h = f2bf(v);
      if (k & 1) WoT2[(size_t)c*160 + ((kb+k)>>1)] = prev | ((unsigned)h<<16);
      else       prev = (unsigned)h;
    }
    return;
  }
  __shared__ u16 xh[64*264];     // bf16 x tile [row][k], stride 264 (33.8KB)
  __shared__ u16 whT[32*264];    // bf16 Wh^T [col][k], stride 264 (16.9KB)
  const int t = threadIdx.x;
  const int wv = t >> 6, l = t & 63;
  const int r0 = blockIdx.x * 64;

  // stage xh: coalesced float4 loads of x, cvt_pk to bf16
  const float4* xg = (const float4*)(x + (size_t)r0*256);
  #pragma unroll
  for (int i=0;i<16;++i){
    int f = t + 256*i;
    int row = f >> 6, c4 = f & 63;
    float4 v = xg[f];
    unsigned p0,p1;
    asm("v_cvt_pk_bf16_f32 %0, %1, %2" : "=v"(p0) : "v"(v.x), "v"(v.y));
    asm("v_cvt_pk_bf16_f32 %0, %1, %2" : "=v"(p1) : "v"(v.z), "v"(v.w));
    uint2 pk = {p0, p1};
    *(uint2*)&xh[row*264 + c4*4] = pk;
  }
  // stage whT: Wh [256][32] f32 -> whT[col][k] bf16 (coalesced row reads)
  #pragma unroll
  for (int i=0;i<32;++i){
    int k = i*8 + (t>>5);
    int col = t & 31;
    whT[col*264 + k] = f2bf(Wh[(size_t)k*32 + col]);
  }

  // s: fp32 exact from global x (L2-hot). row = t>>2, k-quarter = t&3.
  {
    int row = t >> 2, kq = t & 3;
    float a0=0.f,a1=0.f,a2=0.f,a3=0.f;
    const float4* wsr = (const float4*)Ws;   // Ws[k][0..3]
    const float4* xr = (const float4*)(x + (size_t)(r0+row)*256 + kq*64);
    #pragma unroll
    for (int i=0;i<16;++i){
      int c4 = kq*16 + i;
      float4 xv = xr[i];
      float4 w0 = wsr[c4*4+0], w1 = wsr[c4*4+1], w2 = wsr[c4*4+2], w3 = wsr[c4*4+3];
      a0 += xv.x*w0.x + xv.y*w1.x + xv.z*w2.x + xv.w*w3.x;
      a1 += xv.x*w0.y + xv.y*w1.y + xv.z*w2.y + xv.w*w3.y;
      a2 += xv.x*w0.z + xv.y*w1.z + xv.z*w2.z + xv.w*w3.z;
      a3 += xv.x*w0.w + xv.y*w1.w + xv.z*w2.w + xv.w*w3.w;
    }
    a0 += __shfl_xor(a0,1); a0 += __shfl_xor(a0,2);
    a1 += __shfl_xor(a1,1); a1 += __shfl_xor(a1,2);
    a2 += __shfl_xor(a2,1); a2 += __shfl_xor(a2,2);
    a3 += __shfl_xor(a3,1); a3 += __shfl_xor(a3,2);
    if (kq == 0){
      float4 sv = { a0+bs[0], a1+bs[1], a2+bs[2], a3+bs[3] };
      ((float4*)sOut)[r0 + row] = sv;
      // A-side (point) fragment: k0-7 = [hi4,hi4]; k8-15 = [lo4, nh, nl, 1, 1]
      u16 h0=f2bf(sv.x), h1=f2bf(sv.y), h2=f2bf(sv.z), h3=f2bf(sv.w);
      float e0 = sv.x - __uint_as_float((unsigned)h0<<16);
      float e1 = sv.y - __uint_as_float((unsigned)h1<<16);
      float e2 = sv.z - __uint_as_float((unsigned)h2<<16);
      float e3 = sv.w - __uint_as_float((unsigned)h3<<16);
      u16 l0=f2bf(e0), l1=f2bf(e1), l2=f2bf(e2), l3=f2bf(e3);
      float n = sv.x*sv.x + sv.y*sv.y + sv.z*sv.z + sv.w*sv.w;
      u16 nh = f2bf(n);
      u16 nl = f2bf(n - __uint_as_float((unsigned)nh<<16));
      uint4 w0, w1;
      w0.x = (unsigned)h0 | ((unsigned)h1<<16);
      w0.y = (unsigned)h2 | ((unsigned)h3<<16);
      w0.z = w0.x; w0.w = w0.y;
      w1.x = (unsigned)l0 | ((unsigned)l1<<16);
      w1.y = (unsigned)l2 | ((unsigned)l3<<16);
      w1.z = (unsigned)nh | ((unsigned)nl<<16);
      w1.w = 0x3F803F80u;                       // 1.0, 1.0 (pairs with B's si2 hi/lo)
      sfrag[(size_t)(r0+row)*2 + 0] = w0;
      sfrag[(size_t)(r0+row)*2 + 1] = w1;
    }
  }
  __syncthreads();

  // h = x @ Wh via MFMA: wave wv -> rows 16wv..16wv+15; 2 col-tiles of 16.
  {
    const int lq = l & 15, g = l >> 4;
    const f32x4 zero = {0.f,0.f,0.f,0.f};
    f32x4 h0 = zero, h1 = zero;
    #pragma unroll
    for (int ks=0; ks<8; ++ks){
      short8 a  = *(const short8*)&xh[(wv*16+lq)*264 + ks*32 + g*8];
      short8 b0 = *(const short8*)&whT[lq*264       + ks*32 + g*8];
      short8 b1 = *(const short8*)&whT[(16+lq)*264  + ks*32 + g*8];
      h0 = __builtin_amdgcn_mfma_f32_16x16x32_bf16(a, b0, h0, 0,0,0);
      h1 = __builtin_amdgcn_mfma_f32_16x16x32_bf16(a, b1, h1, 0,0,0);
    }
    float bv0 = bh[lq], bv1 = bh[16+lq];
    #pragma unroll
    for (int rg=0; rg<4; ++rg){
      int rowg = r0 + wv*16 + g*4 + rg;
      hOut[(size_t)rowg*32 + lq]      = f2bf(h0[rg] + bv0);
      hOut[(size_t)rowg*32 + 16 + lq] = f2bf(h1[rg] + bv1);
    }
  }
}

// ---------------- Kernel B: half-sample quarter-octave radix-select, lean scan loops --
// 2048 blocks; block: 16 queries, 4 waves each scanning a 1024-pt quarter.
// Pass 1 (32 tiles/wave = half sample): 128 quarter-octave bins (u>>21 window) -> tau.
// Pass 2 (64 tiles/wave): push survivor indices (u < tau) to slist; scnt counts ALL.
// Final (ALL 4 waves, stride 16): exact fp32 d^2; overflow -> exact full-scan fallback.
#define BUBBLE16(v)                                              \
  { _Pragma("unroll")                                            \
    for (int k=0;k<16;++k){                                      \
      unsigned int mn = (v) < bp[k] ? (v) : bp[k];               \
      unsigned int mx = (v) < bp[k] ? bp[k] : (v);               \
      bp[k] = mn; (v) = mx;                                      \
    } }

#define MERGE16(OT)                                              \
  { unsigned int c[16];                                          \
    _Pragma("unroll")                                            \
    for (int k=0;k<16;++k){ unsigned int b2 = (OT)[15-k];        \
      c[k] = bp[k] < b2 ? bp[k] : b2; }                          \
    _Pragma("unroll")                                            \
    for (int d=8; d>=1; d>>=1){                                  \
      _Pragma("unroll")                                          \
      for (int i=0;i<16;++i){                                    \
        if ((i & d) == 0){                                       \
          unsigned int lo = c[i] < c[i+d] ? c[i] : c[i+d];       \
          unsigned int hi = c[i] < c[i+d] ? c[i+d] : c[i];       \
          c[i] = lo; c[i+d] = hi;                                \
        }                                                        \
      }                                                          \
    }                                                            \
    _Pragma("unroll")                                            \
    for (int k=0;k<16;++k) bp[k] = c[k]; }

#define SCAP 512
#define BIN_LO 440u   // 110*4: window start (exp 110 -> d2 ~ 4e-6)

#define P1BODY(F, TL)                                            \
  { union { uint4 q; short8 v; } au; au.q = (F);                 \
    if (ld) (F) = fw[(size_t)((TL)+4)*32 + a32];                 \
    f32x4 acc = __builtin_amdgcn_mfma_f32_16x16x32_bf16(au.v, bq, zacc, 0,0,0); \
    _Pragma("unroll")                                            \
    for (int rg=0; rg<4; ++rg){                                  \
      unsigned u = __float_as_uint(fmaxf(acc[rg],0.f));          \
      unsigned q21 = u >> 21;                                    \
      unsigned b = (q21 < BIN_LO) ? 0u : umin_(q21 - BIN_LO, 127u); \
      atomicAdd(&hist[hbase + b], 1u);                           \
    } }

#define P2BODY(F, TL)                                            \
  { union { uint4 q; short8 v; } au; au.q = (F);                 \
    if (ld) (F) = fw[(size_t)((TL)+4)*32 + a32];                 \
    f32x4 acc = __builtin_amdgcn_mfma_f32_16x16x32_bf16(au.v, bq, zacc, 0,0,0); \
    const int jb = jt + (TL)*16;                                 \
    _Pragma("unroll")                                            \
    for (int rg=0; rg<4; ++rg){                                  \
      unsigned u = __float_as_uint(fmaxf(acc[rg],0.f));          \
      if (u < tauB){                                             \
        unsigned idx = atomicAdd(&scnt[q16], 1u);                \
        if (idx < (unsigned)SCAP) slist[q16*SCAP + idx] = (u16)(jb + rg); \
      }                                                          \
    } }

__global__ __launch_bounds__(256, 8) void kB(
    const float* __restrict__ sIn, const uint4* __restrict__ sfrag,
    const unsigned short* __restrict__ hIn, unsigned short* __restrict__ Umini)
{
  __shared__ unsigned int hist[16*129];    // per-query 128 quarter-octave bins, stride 129
  __shared__ u16 slist[16*SCAP];           // per-query survivor indices
  __shared__ unsigned int scnt[16];
  __shared__ unsigned int tauL[16];
  __shared__ unsigned int mrg[48][17];     // cross-wave merge lists (waves 1-3)
  const int t = threadIdx.x;
  const int wv = t >> 6, l = t & 63;
  const int e = blockIdx.x >> 8;           // 256 blocks/event
  const int qblk = (blockIdx.x & 255) * 16;
  const int q16 = l & 15, g = l >> 4;
  const int qloc = qblk + q16;

  const float4* sg = (const float4*)sIn;
  const float4 sq = sg[(size_t)e*EV + qloc];
  const float si2 = sq.x*sq.x + sq.y*sq.y + sq.z*sq.z + sq.w*sq.w;

  // B (query) fragment: g0: [-2s hi4 | -2s lo4]; g1: [-2s hi4 | 1, 1, si2h, si2l]
  union BU { u16 u[8]; short8 v; } bu;
  #pragma unroll
  for (int i2=0;i2<8;++i2) bu.u[i2]=0;
  {
    float tx=-2.f*sq.x, ty=-2.f*sq.y, tz=-2.f*sq.z, tw=-2.f*sq.w;
    u16 h0=f2bf(tx), h1=f2bf(ty), h2=f2bf(tz), h3=f2bf(tw);
    if (g==0){
      float e0 = tx - __uint_as_float((unsigned)h0<<16);
      float e1 = ty - __uint_as_float((unsigned)h1<<16);
      float e2 = tz - __uint_as_float((unsigned)h2<<16);
      float e3 = tw - __uint_as_float((unsigned)h3<<16);
      bu.u[0]=h0; bu.u[1]=h1; bu.u[2]=h2; bu.u[3]=h3;
      bu.u[4]=f2bf(e0); bu.u[5]=f2bf(e1); bu.u[6]=f2bf(e2); bu.u[7]=f2bf(e3);
    } else if (g==1){
      u16 sh = f2bf(si2);
      u16 sl = f2bf(si2 - __uint_as_float((unsigned)sh<<16));
      bu.u[0]=h0; bu.u[1]=h1; bu.u[2]=h2; bu.u[3]=h3;
      bu.u[4]=0x3F80; bu.u[5]=0x3F80; bu.u[6]=sh; bu.u[7]=sl;
    }
  }
  const short8 bq = bu.v;

  // zero histogram + counters
  for (int i=t; i<16*129; i+=256) hist[i]=0;
  if (t < 16) scnt[t] = 0;
  __syncthreads();

  const f32x4 zacc = {0.f,0.f,0.f,0.f};
  const uint4 zf4 = {0,0,0,0};
  const uint4* fw = sfrag + (((size_t)e*EV + wv*1024) << 1);
  const int a32 = q16*2 + g;               // lanes 0-31 load the 2 uint4 halves of point q16
  const bool ld = (l < 32);
  const int hbase = q16*129;

  // ---- pass 1: quarter-octave histogram over first 512 pts of the quarter ----
  {
    uint4 f0 = ld ? fw[a32]      : zf4;
    uint4 f1 = ld ? fw[32 + a32] : zf4;
    uint4 f2 = ld ? fw[64 + a32] : zf4;
    uint4 f3 = ld ? fw[96 + a32] : zf4;
    for (int tl=0; tl<32; tl+=4){
      P1BODY(f0, tl+0)
      P1BODY(f1, tl+1)
      P1BODY(f2, tl+2)
      P1BODY(f3, tl+3)
    }
  }
  __syncthreads();

  // ---- prefix: find tau per query (16 threads per query, chunks of 8 bins) ----
  {
    int q = t >> 4, i = t & 15;
    int base = q*129 + i*8;
    unsigned cs = 0;
    #pragma unroll
    for (int k2=0;k2<8;++k2) cs += hist[base+k2];
    unsigned ps = cs;
    #pragma unroll
    for (int d=1; d<16; d<<=1){
      unsigned o = __shfl_up(ps, d, 16);
      if ((t&15) >= d) ps += o;
    }
    if (ps >= 16u && (ps - cs) < 16u){
      unsigned run = ps - cs;
      unsigned B = 127;
      #pragma unroll
      for (int k2=0;k2<8;++k2){
        unsigned c2 = hist[base+k2];
        bool hit = (run < 16u) && (run + c2 >= 16u);
        if (hit) B = (unsigned)(i*8 + k2);
        run += c2;
      }
      // bin 127 is open-ended (clamped): cannot bound its members -> force fallback
      tauL[q] = (B >= 127u) ? 0x7F800001u : ((BIN_LO + B + 1u) << 21);
    }
  }
  __syncthreads();
  const unsigned tauB = tauL[q16];

  // ---- pass 2: full quarter scan, push survivor indices (scnt counts ALL) ----
  {
    uint4 f0 = ld ? fw[a32]      : zf4;
    uint4 f1 = ld ? fw[32 + a32] : zf4;
    uint4 f2 = ld ? fw[64 + a32] : zf4;
    uint4 f3 = ld ? fw[96 + a32] : zf4;
    const int jt = wv*1024 + g*4;
    for (int tl=0; tl<64; tl+=4){
      P2BODY(f0, tl+0)
      P2BODY(f1, tl+1)
      P2BODY(f2, tl+2)
      P2BODY(f3, tl+3)
    }
  }
  __syncthreads();

  // ---- final: exact fp32 d^2 -> top-16; ALL 4 waves share the work (stride 16) ----
  unsigned scn_raw = scnt[q16];
  unsigned int bp[16];
  #pragma unroll
  for (int k=0;k<16;++k) bp[k]=0xFFFFFFFFu;
  const int lane16 = wv*4 + g;             // 0..15 within each query's 16 helper lanes
  if (scn_raw > (unsigned)SCAP){
    // overflow fallback: exact scan of all EV points (correctness guarantee, cold)
    for (int jj=lane16; jj<EV; jj+=16){
      float4 s4 = sg[(size_t)e*EV + jj];
      float dx = sq.x-s4.x, dy = sq.y-s4.y, dz = sq.z-s4.z, dw = sq.w-s4.w;
      float d2 = dx*dx + dy*dy + dz*dz + dw*dw;
      unsigned key = (__float_as_uint(d2) & 0xFFFFF000u) | (unsigned)jj;
      if (key < bp[15]) { BUBBLE16(key) }
    }
  } else {
    for (unsigned i=lane16; i<scn_raw; i+=16){
      int jj = (int)slist[q16*SCAP + i];
      float4 s4 = sg[(size_t)e*EV + jj];
      float dx = sq.x-s4.x, dy = sq.y-s4.y, dz = sq.z-s4.z, dw = sq.w-s4.w;
      float d2 = dx*dx + dy*dy + dz*dz + dw*dw;
      unsigned key = (__float_as_uint(d2) & 0xFFFFF000u) | (unsigned)jj;
      BUBBLE16(key)
    }
  }

  // in-wave merge across the 4 rowgrp-lanes of each query (xor 16, then xor 32)
  #pragma unroll
  for (int st=0; st<2; ++st){
    const int msk = (st==0) ? 16 : 32;
    unsigned int ot[16];
    #pragma unroll
    for (int k=0;k<16;++k) ot[k] = (unsigned int)__shfl_xor((int)bp[k], msk, 64);
    MERGE16(ot)
  }

  // cross-wave merge: waves 1-3 publish, wave 0 merges + aggregates
  if (wv != 0 && l < 16){
    #pragma unroll
    for (int k=0;k<16;++k) mrg[(wv-1)*16 + l][k] = bp[k];
  }
  __syncthreads();
  if (wv != 0) return;
  #pragma unroll
  for (int w=0; w<3; ++w){
    unsigned int ot[16];
    #pragma unroll
    for (int k=0;k<16;++k) ot[k] = mrg[w*16 + q16][k];
    MERGE16(ot)
  }

  // aggregation: lane (q16, g) owns features g*8..g*8+7 for all 16 neighbors
  float am[8], ax[8];
  #pragma unroll
  for (int p=0;p<8;++p){ am[p]=0.f; ax[p]=-3.4e38f; }
  const uint4* hb = (const uint4*)(hIn + (size_t)e*EV*32);
  #pragma unroll
  for (int i=0;i<16;++i){
    unsigned int key = bp[i];
    int j = (int)(key & 0xFFFu);
    float d2 = __uint_as_float(key & 0xFFFFF000u);
    float w = __expf(-10.f * d2);
    uint4 hv = hb[(size_t)j*4 + g];
    unsigned int uu[4] = {hv.x, hv.y, hv.z, hv.w};
    #pragma unroll
    for (int c2=0;c2<4;++c2){
      float flo = __uint_as_float(uu[c2] << 16);
      float fhi = __uint_as_float(uu[c2] & 0xFFFF0000u);
      float m0 = w*flo, m1 = w*fhi;
      am[c2*2]   += m0;                 am[c2*2+1] += m1;
      ax[c2*2]    = fmaxf(ax[c2*2],m0); ax[c2*2+1]  = fmaxf(ax[c2*2+1],m1);
    }
  }
  {
    unsigned short* Ur = Umini + ((size_t)e*EV + qloc)*64;
    uint4 pm, px;
    pm.x = (unsigned)f2bf(am[0]*(1.f/16.f)) | ((unsigned)f2bf(am[1]*(1.f/16.f))<<16);
    pm.y = (unsigned)f2bf(am[2]*(1.f/16.f)) | ((unsigned)f2bf(am[3]*(1.f/16.f))<<16);
    pm.z = (unsigned)f2bf(am[4]*(1.f/16.f)) | ((unsigned)f2bf(am[5]*(1.f/16.f))<<16);
    pm.w = (unsigned)f2bf(am[6]*(1.f/16.f)) | ((unsigned)f2bf(am[7]*(1.f/16.f))<<16);
    px.x = (unsigned)f2bf(ax[0]) | ((unsigned)f2bf(ax[1])<<16);
    px.y = (unsigned)f2bf(ax[2]) | ((unsigned)f2bf(ax[3])<<16);
    px.z = (unsigned)f2bf(ax[4]) | ((unsigned)f2bf(ax[5])<<16);
    px.w = (unsigned)f2bf(ax[6]) | ((unsigned)f2bf(ax[7])<<16);
    *(uint4*)(Ur +  0 + g*8) = pm;
    *(uint4*)(Ur + 32 + g*8) = px;
  }
}

// ---------------- Kernel C: x_new = [bf16(x)|Umini] @ Wo + bo ; residual ; LayerNorm ----
__global__ __launch_bounds__(256, 4) void kC(
    const unsigned short* __restrict__ Umini, const unsigned short* __restrict__ WoT,
    const float* __restrict__ bo, const float* __restrict__ x,
    const float* __restrict__ gamma, const float* __restrict__ beta,
    float* __restrict__ out)
{
  __shared__ unsigned short At[64*40];    // [64 rows][32k padded to 40]
  __shared__ unsigned short Bt[256*40];   // [256 cols][32k padded to 40]
  __shared__ float ps[64*4], pq[64*4];
  const int t = threadIdx.x;
  const int r0 = blockIdx.x * 64;
  const int l = t & 63, wv = t >> 6;
  const int lq = l & 15, g = l >> 4;
  f32x4 acc[4][4];
  const f32x4 zero = {0.f,0.f,0.f,0.f};
  #pragma unroll
  for (int m=0;m<4;++m)
    #pragma unroll
    for (int n=0;n<4;++n) acc[m][n] = zero;

  for (int kk=0; kk<10; ++kk){
    const int k0 = kk*32;
    __syncthreads();
    { // stage A: k<256 from x (fp32 -> bf16 via v_cvt_pk), else from Umini
      int row = t >> 2, ko = (t & 3)*8;
      uint4 av;
      if (k0 < 256){
        const float4* xr = (const float4*)(x + (size_t)(r0+row)*256 + k0 + ko);
        float4 u0 = xr[0], u1 = xr[1];
        unsigned p0,p1,p2,p3;
        asm("v_cvt_pk_bf16_f32 %0, %1, %2" : "=v"(p0) : "v"(u0.x), "v"(u0.y));
        asm("v_cvt_pk_bf16_f32 %0, %1, %2" : "=v"(p1) : "v"(u0.z), "v"(u0.w));
        asm("v_cvt_pk_bf16_f32 %0, %1, %2" : "=v"(p2) : "v"(u1.x), "v"(u1.y));
        asm("v_cvt_pk_bf16_f32 %0, %1, %2" : "=v"(p3) : "v"(u1.z), "v"(u1.w));
        av.x = p0; av.y = p1; av.z = p2; av.w = p3;
      } else {
        av = *(const uint4*)(Umini + (size_t)(r0+row)*64 + (k0-256) + ko);
      }
      *(uint4*)(At + row*40 + ko) = av;
    }
    { // stage B^T from pre-transposed WoT [256 cols][320 k] bf16
      int col = t;
      const uint4* src = (const uint4*)(WoT + (size_t)col*320 + k0);
      #pragma unroll
      for (int j=0;j<4;++j) *(uint4*)(Bt + col*40 + j*8) = src[j];
    }
    __syncthreads();
    short8 a[4], b[4];
    #pragma unroll
    for (int m=0;m<4;++m) a[m] = *(const short8*)(At + (16*m+lq)*40 + g*8);
    #pragma unroll
    for (int n=0;n<4;++n) b[n] = *(const short8*)(Bt + (wv*64 + 16*n + lq)*40 + g*8);
    #pragma unroll
    for (int m=0;m<4;++m)
      #pragma unroll
      for (int n=0;n<4;++n)
        acc[m][n] = __builtin_amdgcn_mfma_f32_16x16x32_bf16(a[m], b[n], acc[m][n], 0, 0, 0);
  }

  // epilogue: + bo + x(residual), LayerNorm over 256 cols
  float bo_n[4], ga_n[4], be_n[4];
  #pragma unroll
  for (int n=0;n<4;++n){
    int colg = wv*64 + 16*n + lq;
    bo_n[n] = bo[colg]; ga_n[n] = gamma[colg]; be_n[n] = beta[colg];
  }
  float pr[4][4], pr2[4][4];
  #pragma unroll
  for (int m=0;m<4;++m){
    #pragma unroll
    for (int rg=0;rg<4;++rg){
      int rowg = r0 + 16*m + g*4 + rg;
      float sum=0.f, sq=0.f;
      #pragma unroll
      for (int n=0;n<4;++n){
        int colg = wv*64 + 16*n + lq;
        float y = acc[m][n][rg] + bo_n[n] + x[(size_t)rowg*256 + colg];
        acc[m][n][rg] = y;
        sum += y; sq += y*y;
      }
      sum += __shfl_xor(sum,1); sq += __shfl_xor(sq,1);
      sum += __shfl_xor(sum,2); sq += __shfl_xor(sq,2);
      sum += __shfl_xor(sum,4); sq += __shfl_xor(sq,4);
      sum += __shfl_xor(sum,8); sq += __shfl_xor(sq,8);
      pr[m][rg]=sum; pr2[m][rg]=sq;
    }
  }
  if (lq == 0){
    #pragma unroll
    for (int m=0;m<4;++m)
      #pragma unroll
      for (int rg=0;rg<4;++rg){
        int rowl = 16*m + g*4 + rg;
        ps[rowl*4 + wv] = pr[m][rg];
        pq[rowl*4 + wv] = pr2[m][rg];
      }
  }
  __syncthreads();
  #pragma unroll
  for (int m=0;m<4;++m){
    #pragma unroll
    for (int rg=0;rg<4;++rg){
      int rowl = 16*m + g*4 + rg;
      float sum = ps[rowl*4+0]+ps[rowl*4+1]+ps[rowl*4+2]+ps[rowl*4+3];
      float sq  = pq[rowl*4+0]+pq[rowl*4+1]+pq[rowl*4+2]+pq[rowl*4+3];
      float mu  = sum * (1.f/256.f);
      float var = sq * (1.f/256.f) - mu*mu;
      float inv = rsqrtf(var + 1e-5f);
      int rowg = r0 + rowl;
      #pragma unroll
      for (int n=0;n<4;++n){
        int colg = wv*64 + 16*n + lq;
        out[(size_t)rowg*256 + colg] = ga_n[n]*(acc[m][n][rg] - mu)*inv + be_n[n];
      }
    }
  }
}

extern "C" void kernel_launch(void* const* d_in, const int* in_sizes, int n_in,
                              void* d_out, int out_size, void* d_ws, size_t ws_size,
                              hipStream_t stream)
{
  const float* x     = (const float*)d_in[0];
  // d_in[1] = batch_index (block-sorted equal events; unused)
  const float* Ws    = (const float*)d_in[2];
  const float* bs    = (const float*)d_in[3];
  const float* Wh    = (const float*)d_in[4];
  const float* bh    = (const float*)d_in[5];
  const float* Wo    = (const float*)d_in[6];
  const float* bo    = (const float*)d_in[7];
  const float* gamma = (const float*)d_in[8];
  const float* beta  = (const float*)d_in[9];
  float* out = (float*)d_out;

  char* ws = (char*)d_ws;
  float*          sBuf  = (float*)ws;                        // N*4 f32    = 0.5 MB
  uint4*          sfrag = (uint4*)(ws + 524288);             // N*32 B     = 1 MB
  unsigned short* hBuf  = (unsigned short*)(ws + 1572864);   // N*32 bf16  = 2 MB
  unsigned short* Umini = (unsigned short*)(ws + 3670016);   // N*64 bf16  = 4 MB
  unsigned short* WoT   = (unsigned short*)(ws + 7864320);   // 256*320 bf16 = 160 KB

  kA<<<dim3(N_TOT/64 + 10), dim3(256), 0, stream>>>(x, Ws, bs, Wh, bh, Wo,
                                                    sBuf, sfrag, hBuf, (unsigned int*)WoT);
  kB<<<dim3(N_TOT/16), dim3(256), 0, stream>>>(sBuf, sfrag, hBuf, Umini);
  kC<<<dim3(N_TOT/64), dim3(256), 0, stream>>>(Umini, WoT, bo, x, gamma, beta, out);
}

// Round 12
// 132.885 us; speedup vs baseline: 2.8641x; 1.1184x over previous
//
#include <hip/hip_runtime.h>
#include <stdint.h>

typedef short short8 __attribute__((ext_vector_type(8)));
typedef float f32x4 __attribute__((ext_vector_type(4)));
typedef unsigned short u16;

#define N_TOT 32768
#define EV 4096

__device__ __forceinline__ u16 f2bf(float f){
  unsigned int x = __float_as_uint(f);
  x += 0x7FFFu + ((x >> 16) & 1u);
  return (u16)(x >> 16);
}
__device__ __forceinline__ unsigned umin_(unsigned a, unsigned b){ return a<b?a:b; }

// ---------------- Kernel A: fused stage+s (single x pass), h (bf16 MFMA); +kW fold ---
__global__ __launch_bounds__(256, 3) void kA(
    const float* __restrict__ x, const float* __restrict__ Ws,
    const float* __restrict__ bs, const float* __restrict__ Wh,
    const float* __restrict__ bh, const float* __restrict__ Wo,
    float* __restrict__ sOut, uint4* __restrict__ sfrag,
    unsigned short* __restrict__ hOut, unsigned int* __restrict__ WoT2)
{
  if (blockIdx.x >= N_TOT/64){                 // folded kW: Wo [320][256] f32 -> WoT [256][320] bf16
    const int kb = (blockIdx.x - N_TOT/64) * 32;
    const int c = threadIdx.x;
    unsigned int prev = 0;
    for (int k=0;k<32;++k){
      float v = Wo[(size_t)(kb+k)*256 + c];
      u16 h = f2bf(v);
      if (k & 1) WoT2[(size_t)c*160 + ((kb+k)>>1)] = prev | ((unsigned)h<<16);
      else       prev = (unsigned)h;
    }
    return;
  }
  __shared__ u16 xh[64*264];     // bf16 x tile [row][k], stride 264 u16 (33.8KB)
  __shared__ u16 whT[32*264];    // bf16 Wh^T [col][k], stride 264 (16.9KB)
  const int t = threadIdx.x;
  const int wv = t >> 6, l = t & 63;
  const int r0 = blockIdx.x * 64;

  // stage whT: Wh [256][32] f32 -> whT[col][k] bf16
  #pragma unroll
  for (int i=0;i<32;++i){
    int k = i*8 + (t>>5);
    int col = t & 31;
    whT[col*264 + k] = f2bf(Wh[(size_t)k*32 + col]);
  }

  // fused: stage xh (bf16) + s fp32 partials, ONE pass over x.
  // thread t: row = t>>2, chunks c4 = (t&3) + 4*i  (4 threads/row, 64B-coalesced)
  {
    const int row = t >> 2, c40 = t & 3;
    const float4* xr = (const float4*)(x + (size_t)(r0+row)*256);
    const float4* wsr = (const float4*)Ws;   // Ws[k][0..3]
    float a0=0.f,a1=0.f,a2=0.f,a3=0.f;
    #pragma unroll
    for (int i=0;i<16;++i){
      int c4 = c40 + i*4;
      float4 xv = xr[c4];
      unsigned p0,p1;
      asm("v_cvt_pk_bf16_f32 %0, %1, %2" : "=v"(p0) : "v"(xv.x), "v"(xv.y));
      asm("v_cvt_pk_bf16_f32 %0, %1, %2" : "=v"(p1) : "v"(xv.z), "v"(xv.w));
      uint2 pk = {p0, p1};
      *(uint2*)&xh[row*264 + c4*4] = pk;
      float4 w0 = wsr[c4*4+0], w1 = wsr[c4*4+1], w2 = wsr[c4*4+2], w3 = wsr[c4*4+3];
      a0 += xv.x*w0.x + xv.y*w1.x + xv.z*w2.x + xv.w*w3.x;
      a1 += xv.x*w0.y + xv.y*w1.y + xv.z*w2.y + xv.w*w3.y;
      a2 += xv.x*w0.z + xv.y*w1.z + xv.z*w2.z + xv.w*w3.z;
      a3 += xv.x*w0.w + xv.y*w1.w + xv.z*w2.w + xv.w*w3.w;
    }
    a0 += __shfl_xor(a0,1); a0 += __shfl_xor(a0,2);
    a1 += __shfl_xor(a1,1); a1 += __shfl_xor(a1,2);
    a2 += __shfl_xor(a2,1); a2 += __shfl_xor(a2,2);
    a3 += __shfl_xor(a3,1); a3 += __shfl_xor(a3,2);
    if (c40 == 0){
      float4 sv = { a0+bs[0], a1+bs[1], a2+bs[2], a3+bs[3] };
      ((float4*)sOut)[r0 + row] = sv;
      // A-side (point) fragment: k0-7 = [hi4,hi4]; k8-15 = [lo4, nh, nl, 1, 1]
      u16 h0=f2bf(sv.x), h1=f2bf(sv.y), h2=f2bf(sv.z), h3=f2bf(sv.w);
      float e0 = sv.x - __uint_as_float((unsigned)h0<<16);
      float e1 = sv.y - __uint_as_float((unsigned)h1<<16);
      float e2 = sv.z - __uint_as_float((unsigned)h2<<16);
      float e3 = sv.w - __uint_as_float((unsigned)h3<<16);
      u16 l0=f2bf(e0), l1=f2bf(e1), l2=f2bf(e2), l3=f2bf(e3);
      float n = sv.x*sv.x + sv.y*sv.y + sv.z*sv.z + sv.w*sv.w;
      u16 nh = f2bf(n);
      u16 nl = f2bf(n - __uint_as_float((unsigned)nh<<16));
      uint4 w0, w1;
      w0.x = (unsigned)h0 | ((unsigned)h1<<16);
      w0.y = (unsigned)h2 | ((unsigned)h3<<16);
      w0.z = w0.x; w0.w = w0.y;
      w1.x = (unsigned)l0 | ((unsigned)l1<<16);
      w1.y = (unsigned)l2 | ((unsigned)l3<<16);
      w1.z = (unsigned)nh | ((unsigned)nl<<16);
      w1.w = 0x3F803F80u;                       // 1.0, 1.0 (pairs with B's si2 hi/lo)
      sfrag[(size_t)(r0+row)*2 + 0] = w0;
      sfrag[(size_t)(r0+row)*2 + 1] = w1;
    }
  }
  __syncthreads();

  // h = x @ Wh via MFMA: wave wv -> rows 16wv..16wv+15; 2 col-tiles of 16.
  {
    const int lq = l & 15, g = l >> 4;
    const f32x4 zero = {0.f,0.f,0.f,0.f};
    f32x4 h0 = zero, h1 = zero;
    #pragma unroll
    for (int ks=0; ks<8; ++ks){
      short8 a  = *(const short8*)&xh[(wv*16+lq)*264 + ks*32 + g*8];
      short8 b0 = *(const short8*)&whT[lq*264       + ks*32 + g*8];
      short8 b1 = *(const short8*)&whT[(16+lq)*264  + ks*32 + g*8];
      h0 = __builtin_amdgcn_mfma_f32_16x16x32_bf16(a, b0, h0, 0,0,0);
      h1 = __builtin_amdgcn_mfma_f32_16x16x32_bf16(a, b1, h1, 0,0,0);
    }
    float bv0 = bh[lq], bv1 = bh[16+lq];
    #pragma unroll
    for (int rg=0; rg<4; ++rg){
      int rowg = r0 + wv*16 + g*4 + rg;
      hOut[(size_t)rowg*32 + lq]      = f2bf(h0[rg] + bv0);
      hOut[(size_t)rowg*32 + 16 + lq] = f2bf(h1[rg] + bv1);
    }
  }
}

// ---------------- Kernel B: quarter-sample quarter-octave radix-select ---------------
// 2048 blocks; block: 16 queries, 4 waves each scanning a 1024-pt quarter.
// Pass 1 (16 tiles/wave = quarter sample): 128 quarter-octave bins (u>>21) -> tau.
// Pass 2 (64 tiles/wave): signed-compare survivor push (includes negative-rounded
//   self-distances); scnt counts ALL (overflow -> exact full-scan fallback).
// Final (ALL 4 waves, stride 16): exact fp32 d^2 -> bubble -> merge -> aggregate.
#define BUBBLE16(v)                                              \
  { _Pragma("unroll")                                            \
    for (int k=0;k<16;++k){                                      \
      unsigned int mn = (v) < bp[k] ? (v) : bp[k];               \
      unsigned int mx = (v) < bp[k] ? bp[k] : (v);               \
      bp[k] = mn; (v) = mx;                                      \
    } }

#define MERGE16(OT)                                              \
  { unsigned int c[16];                                          \
    _Pragma("unroll")                                            \
    for (int k=0;k<16;++k){ unsigned int b2 = (OT)[15-k];        \
      c[k] = bp[k] < b2 ? bp[k] : b2; }                          \
    _Pragma("unroll")                                            \
    for (int d=8; d>=1; d>>=1){                                  \
      _Pragma("unroll")                                          \
      for (int i=0;i<16;++i){                                    \
        if ((i & d) == 0){                                       \
          unsigned int lo = c[i] < c[i+d] ? c[i] : c[i+d];       \
          unsigned int hi = c[i] < c[i+d] ? c[i+d] : c[i];       \
          c[i] = lo; c[i+d] = hi;                                \
        }                                                        \
      }                                                          \
    }                                                            \
    _Pragma("unroll")                                            \
    for (int k=0;k<16;++k) bp[k] = c[k]; }

#define SCAP 512
#define BIN_LO 440u   // 110*4: window start (exp 110 -> d2 ~ 4e-6)

#define P1BODY(F, TL)                                            \
  { union { uint4 q; short8 v; } au; au.q = (F);                 \
    if (ld) (F) = fw[(size_t)((TL)+4)*32 + a32];                 \
    f32x4 acc = __builtin_amdgcn_mfma_f32_16x16x32_bf16(au.v, bq, zacc, 0,0,0); \
    _Pragma("unroll")                                            \
    for (int rg=0; rg<4; ++rg){                                  \
      unsigned u = __float_as_uint(fmaxf(acc[rg],0.f));          \
      unsigned q21 = u >> 21;                                    \
      unsigned b = (q21 < BIN_LO) ? 0u : umin_(q21 - BIN_LO, 127u); \
      atomicAdd(&hist[hbase + b], 1u);                           \
    } }

#define P2BODY(F, TL)                                            \
  { union { uint4 q; short8 v; } au; au.q = (F);                 \
    if (ld) (F) = fw[(size_t)((TL)+4)*32 + a32];                 \
    f32x4 acc = __builtin_amdgcn_mfma_f32_16x16x32_bf16(au.v, bq, zacc, 0,0,0); \
    const int jb = jt + (TL)*16;                                 \
    _Pragma("unroll")                                            \
    for (int rg=0; rg<4; ++rg){                                  \
      int u = (int)__float_as_uint(acc[rg]);                     \
      if (u < tauS){                                             \
        unsigned idx = atomicAdd(&scnt[q16], 1u);                \
        if (idx < (unsigned)SCAP) slist[q16*SCAP + idx] = (u16)(jb + rg); \
      }                                                          \
    } }

__global__ __launch_bounds__(256, 8) void kB(
    const float* __restrict__ sIn, const uint4* __restrict__ sfrag,
    const unsigned short* __restrict__ hIn, unsigned short* __restrict__ Umini)
{
  __shared__ unsigned int hist[16*129];    // per-query 128 quarter-octave bins, stride 129
  __shared__ u16 slist[16*SCAP];           // per-query survivor indices
  __shared__ unsigned int scnt[16];
  __shared__ unsigned int tauL[16];
  __shared__ unsigned int mrg[48][17];     // cross-wave merge lists (waves 1-3)
  const int t = threadIdx.x;
  const int wv = t >> 6, l = t & 63;
  const int e = blockIdx.x >> 8;           // 256 blocks/event
  const int qblk = (blockIdx.x & 255) * 16;
  const int q16 = l & 15, g = l >> 4;
  const int qloc = qblk + q16;

  const float4* sg = (const float4*)sIn;
  const float4 sq = sg[(size_t)e*EV + qloc];
  const float si2 = sq.x*sq.x + sq.y*sq.y + sq.z*sq.z + sq.w*sq.w;

  // B (query) fragment: g0: [-2s hi4 | -2s lo4]; g1: [-2s hi4 | 1, 1, si2h, si2l]
  union BU { u16 u[8]; short8 v; } bu;
  #pragma unroll
  for (int i2=0;i2<8;++i2) bu.u[i2]=0;
  {
    float tx=-2.f*sq.x, ty=-2.f*sq.y, tz=-2.f*sq.z, tw=-2.f*sq.w;
    u16 h0=f2bf(tx), h1=f2bf(ty), h2=f2bf(tz), h3=f2bf(tw);
    if (g==0){
      float e0 = tx - __uint_as_float((unsigned)h0<<16);
      float e1 = ty - __uint_as_float((unsigned)h1<<16);
      float e2 = tz - __uint_as_float((unsigned)h2<<16);
      float e3 = tw - __uint_as_float((unsigned)h3<<16);
      bu.u[0]=h0; bu.u[1]=h1; bu.u[2]=h2; bu.u[3]=h3;
      bu.u[4]=f2bf(e0); bu.u[5]=f2bf(e1); bu.u[6]=f2bf(e2); bu.u[7]=f2bf(e3);
    } else if (g==1){
      u16 sh = f2bf(si2);
      u16 sl = f2bf(si2 - __uint_as_float((unsigned)sh<<16));
      bu.u[0]=h0; bu.u[1]=h1; bu.u[2]=h2; bu.u[3]=h3;
      bu.u[4]=0x3F80; bu.u[5]=0x3F80; bu.u[6]=sh; bu.u[7]=sl;
    }
  }
  const short8 bq = bu.v;

  // zero histogram + counters
  for (int i=t; i<16*129; i+=256) hist[i]=0;
  if (t < 16) scnt[t] = 0;
  __syncthreads();

  const f32x4 zacc = {0.f,0.f,0.f,0.f};
  const uint4 zf4 = {0,0,0,0};
  const uint4* fw = sfrag + (((size_t)e*EV + wv*1024) << 1);
  const int a32 = q16*2 + g;               // lanes 0-31 load the 2 uint4 halves of point q16
  const bool ld = (l < 32);
  const int hbase = q16*129;

  // ---- pass 1: quarter-octave histogram over first 256 pts of the quarter ----
  {
    uint4 f0 = ld ? fw[a32]      : zf4;
    uint4 f1 = ld ? fw[32 + a32] : zf4;
    uint4 f2 = ld ? fw[64 + a32] : zf4;
    uint4 f3 = ld ? fw[96 + a32] : zf4;
    for (int tl=0; tl<16; tl+=4){
      P1BODY(f0, tl+0)
      P1BODY(f1, tl+1)
      P1BODY(f2, tl+2)
      P1BODY(f3, tl+3)
    }
  }
  __syncthreads();

  // ---- prefix: find tau per query (16 threads per query, chunks of 8 bins) ----
  {
    int q = t >> 4, i = t & 15;
    int base = q*129 + i*8;
    unsigned cs = 0;
    #pragma unroll
    for (int k2=0;k2<8;++k2) cs += hist[base+k2];
    unsigned ps = cs;
    #pragma unroll
    for (int d=1; d<16; d<<=1){
      unsigned o = __shfl_up(ps, d, 16);
      if ((t&15) >= d) ps += o;
    }
    if (ps >= 16u && (ps - cs) < 16u){
      unsigned run = ps - cs;
      unsigned B = 127;
      #pragma unroll
      for (int k2=0;k2<8;++k2){
        unsigned c2 = hist[base+k2];
        bool hit = (run < 16u) && (run + c2 >= 16u);
        if (hit) B = (unsigned)(i*8 + k2);
        run += c2;
      }
      // bin 127 is open-ended (clamped): cannot bound its members -> force fallback
      tauL[q] = (B >= 127u) ? 0x7F800001u : ((BIN_LO + B + 1u) << 21);
    }
  }
  __syncthreads();
  const int tauS = (int)tauL[q16];         // signed compare: negatives (rounded self-d2) survive

  // ---- pass 2: full quarter scan, push survivor indices (scnt counts ALL) ----
  {
    uint4 f0 = ld ? fw[a32]      : zf4;
    uint4 f1 = ld ? fw[32 + a32] : zf4;
    uint4 f2 = ld ? fw[64 + a32] : zf4;
    uint4 f3 = ld ? fw[96 + a32] : zf4;
    const int jt = wv*1024 + g*4;
    for (int tl=0; tl<64; tl+=4){
      P2BODY(f0, tl+0)
      P2BODY(f1, tl+1)
      P2BODY(f2, tl+2)
      P2BODY(f3, tl+3)
    }
  }
  __syncthreads();

  // ---- final: exact fp32 d^2 -> top-16; ALL 4 waves share the work (stride 16) ----
  unsigned scn_raw = scnt[q16];
  unsigned int bp[16];
  #pragma unroll
  for (int k=0;k<16;++k) bp[k]=0xFFFFFFFFu;
  const int lane16 = wv*4 + g;             // 0..15 within each query's 16 helper lanes
  if (scn_raw > (unsigned)SCAP){
    // overflow fallback: exact scan of all EV points (correctness guarantee, cold)
    for (int jj=lane16; jj<EV; jj+=16){
      float4 s4 = sg[(size_t)e*EV + jj];
      float dx = sq.x-s4.x, dy = sq.y-s4.y, dz = sq.z-s4.z, dw = sq.w-s4.w;
      float d2 = dx*dx + dy*dy + dz*dz + dw*dw;
      unsigned key = (__float_as_uint(d2) & 0xFFFFF000u) | (unsigned)jj;
      if (key < bp[15]) { BUBBLE16(key) }
    }
  } else {
    for (unsigned i=lane16; i<scn_raw; i+=16){
      int jj = (int)slist[q16*SCAP + i];
      float4 s4 = sg[(size_t)e*EV + jj];
      float dx = sq.x-s4.x, dy = sq.y-s4.y, dz = sq.z-s4.z, dw = sq.w-s4.w;
      float d2 = dx*dx + dy*dy + dz*dz + dw*dw;
      unsigned key = (__float_as_uint(d2) & 0xFFFFF000u) | (unsigned)jj;
      BUBBLE16(key)
    }
  }

  // in-wave merge across the 4 rowgrp-lanes of each query (xor 16, then xor 32)
  #pragma unroll
  for (int st=0; st<2; ++st){
    const int msk = (st==0) ? 16 : 32;
    unsigned int ot[16];
    #pragma unroll
    for (int k=0;k<16;++k) ot[k] = (unsigned int)__shfl_xor((int)bp[k], msk, 64);
    MERGE16(ot)
  }

  // cross-wave merge: waves 1-3 publish, wave 0 merges + aggregates
  if (wv != 0 && l < 16){
    #pragma unroll
    for (int k=0;k<16;++k) mrg[(wv-1)*16 + l][k] = bp[k];
  }
  __syncthreads();
  if (wv != 0) return;
  #pragma unroll
  for (int w=0; w<3; ++w){
    unsigned int ot[16];
    #pragma unroll
    for (int k=0;k<16;++k) ot[k] = mrg[w*16 + q16][k];
    MERGE16(ot)
  }

  // aggregation: lane (q16, g) owns features g*8..g*8+7 for all 16 neighbors
  float am[8], ax[8];
  #pragma unroll
  for (int p=0;p<8;++p){ am[p]=0.f; ax[p]=-3.4e38f; }
  const uint4* hb = (const uint4*)(hIn + (size_t)e*EV*32);
  #pragma unroll
  for (int i=0;i<16;++i){
    unsigned int key = bp[i];
    int j = (int)(key & 0xFFFu);
    float d2 = __uint_as_float(key & 0xFFFFF000u);
    float w = __expf(-10.f * d2);
    uint4 hv = hb[(size_t)j*4 + g];
    unsigned int uu[4] = {hv.x, hv.y, hv.z, hv.w};
    #pragma unroll
    for (int c2=0;c2<4;++c2){
      float flo = __uint_as_float(uu[c2] << 16);
      float fhi = __uint_as_float(uu[c2] & 0xFFFF0000u);
      float m0 = w*flo, m1 = w*fhi;
      am[c2*2]   += m0;                 am[c2*2+1] += m1;
      ax[c2*2]    = fmaxf(ax[c2*2],m0); ax[c2*2+1]  = fmaxf(ax[c2*2+1],m1);
    }
  }
  {
    unsigned short* Ur = Umini + ((size_t)e*EV + qloc)*64;
    uint4 pm, px;
    pm.x = (unsigned)f2bf(am[0]*(1.f/16.f)) | ((unsigned)f2bf(am[1]*(1.f/16.f))<<16);
    pm.y = (unsigned)f2bf(am[2]*(1.f/16.f)) | ((unsigned)f2bf(am[3]*(1.f/16.f))<<16);
    pm.z = (unsigned)f2bf(am[4]*(1.f/16.f)) | ((unsigned)f2bf(am[5]*(1.f/16.f))<<16);
    pm.w = (unsigned)f2bf(am[6]*(1.f/16.f)) | ((unsigned)f2bf(am[7]*(1.f/16.f))<<16);
    px.x = (unsigned)f2bf(ax[0]) | ((unsigned)f2bf(ax[1])<<16);
    px.y = (unsigned)f2bf(ax[2]) | ((unsigned)f2bf(ax[3])<<16);
    px.z = (unsigned)f2bf(ax[4]) | ((unsigned)f2bf(ax[5])<<16);
    px.w = (unsigned)f2bf(ax[6]) | ((unsigned)f2bf(ax[7])<<16);
    *(uint4*)(Ur +  0 + g*8) = pm;
    *(uint4*)(Ur + 32 + g*8) = px;
  }
}

// ---------------- Kernel C: x_new = [bf16(x)|Umini] @ Wo + bo ; residual ; LayerNorm ----
__global__ __launch_bounds__(256, 4) void kC(
    const unsigned short* __restrict__ Umini, const unsigned short* __restrict__ WoT,
    const float* __restrict__ bo, const float* __restrict__ x,
    const float* __restrict__ gamma, const float* __restrict__ beta,
    float* __restrict__ out)
{
  __shared__ unsigned short At[64*40];    // [64 rows][32k padded to 40]
  __shared__ unsigned short Bt[256*40];   // [256 cols][32k padded to 40]
  __shared__ float ps[64*4], pq[64*4];
  const int t = threadIdx.x;
  const int r0 = blockIdx.x * 64;
  const int l = t & 63, wv = t >> 6;
  const int lq = l & 15, g = l >> 4;
  f32x4 acc[4][4];
  const f32x4 zero = {0.f,0.f,0.f,0.f};
  #pragma unroll
  for (int m=0;m<4;++m)
    #pragma unroll
    for (int n=0;n<4;++n) acc[m][n] = zero;

  for (int kk=0; kk<10; ++kk){
    const int k0 = kk*32;
    __syncthreads();
    { // stage A: k<256 from x (fp32 -> bf16 via v_cvt_pk), else from Umini
      int row = t >> 2, ko = (t & 3)*8;
      uint4 av;
      if (k0 < 256){
        const float4* xr = (const float4*)(x + (size_t)(r0+row)*256 + k0 + ko);
        float4 u0 = xr[0], u1 = xr[1];
        unsigned p0,p1,p2,p3;
        asm("v_cvt_pk_bf16_f32 %0, %1, %2" : "=v"(p0) : "v"(u0.x), "v"(u0.y));
        asm("v_cvt_pk_bf16_f32 %0, %1, %2" : "=v"(p1) : "v"(u0.z), "v"(u0.w));
        asm("v_cvt_pk_bf16_f32 %0, %1, %2" : "=v"(p2) : "v"(u1.x), "v"(u1.y));
        asm("v_cvt_pk_bf16_f32 %0, %1, %2" : "=v"(p3) : "v"(u1.z), "v"(u1.w));
        av.x = p0; av.y = p1; av.z = p2; av.w = p3;
      } else {
        av = *(const uint4*)(Umini + (size_t)(r0+row)*64 + (k0-256) + ko);
      }
      *(uint4*)(At + row*40 + ko) = av;
    }
    { // stage B^T from pre-transposed WoT [256 cols][320 k] bf16
      int col = t;
      const uint4* src = (const uint4*)(WoT + (size_t)col*320 + k0);
      #pragma unroll
      for (int j=0;j<4;++j) *(uint4*)(Bt + col*40 + j*8) = src[j];
    }
    __syncthreads();
    short8 a[4], b[4];
    #pragma unroll
    for (int m=0;m<4;++m) a[m] = *(const short8*)(At + (16*m+lq)*40 + g*8);
    #pragma unroll
    for (int n=0;n<4;++n) b[n] = *(const short8*)(Bt + (wv*64 + 16*n + lq)*40 + g*8);
    #pragma unroll
    for (int m=0;m<4;++m)
      #pragma unroll
      for (int n=0;n<4;++n)
        acc[m][n] = __builtin_amdgcn_mfma_f32_16x16x32_bf16(a[m], b[n], acc[m][n], 0, 0, 0);
  }

  // epilogue: + bo + x(residual), LayerNorm over 256 cols
  float bo_n[4], ga_n[4], be_n[4];
  #pragma unroll
  for (int n=0;n<4;++n){
    int colg = wv*64 + 16*n + lq;
    bo_n[n] = bo[colg]; ga_n[n] = gamma[colg]; be_n[n] = beta[colg];
  }
  float pr[4][4], pr2[4][4];
  #pragma unroll
  for (int m=0;m<4;++m){
    #pragma unroll
    for (int rg=0;rg<4;++rg){
      int rowg = r0 + 16*m + g*4 + rg;
      float sum=0.f, sq=0.f;
      #pragma unroll
      for (int n=0;n<4;++n){
        int colg = wv*64 + 16*n + lq;
        float y = acc[m][n][rg] + bo_n[n] + x[(size_t)rowg*256 + colg];
        acc[m][n][rg] = y;
        sum += y; sq += y*y;
      }
      sum += __shfl_xor(sum,1); sq += __shfl_xor(sq,1);
      sum += __shfl_xor(sum,2); sq += __shfl_xor(sq,2);
      sum += __shfl_xor(sum,4); sq += __shfl_xor(sq,4);
      sum += __shfl_xor(sum,8); sq += __shfl_xor(sq,8);
      pr[m][rg]=sum; pr2[m][rg]=sq;
    }
  }
  if (lq == 0){
    #pragma unroll
    for (int m=0;m<4;++m)
      #pragma unroll
      for (int rg=0;rg<4;++rg){
        int rowl = 16*m + g*4 + rg;
        ps[rowl*4 + wv] = pr[m][rg];
        pq[rowl*4 + wv] = pr2[m][rg];
      }
  }
  __syncthreads();
  #pragma unroll
  for (int m=0;m<4;++m){
    #pragma unroll
    for (int rg=0;rg<4;++rg){
      int rowl = 16*m + g*4 + rg;
      float sum = ps[rowl*4+0]+ps[rowl*4+1]+ps[rowl*4+2]+ps[rowl*4+3];
      float sq  = pq[rowl*4+0]+pq[rowl*4+1]+pq[rowl*4+2]+pq[rowl*4+3];
      float mu  = sum * (1.f/256.f);
      float var = sq * (1.f/256.f) - mu*mu;
      float inv = rsqrtf(var + 1e-5f);
      int rowg = r0 + rowl;
      #pragma unroll
      for (int n=0;n<4;++n){
        int colg = wv*64 + 16*n + lq;
        out[(size_t)rowg*256 + colg] = ga_n[n]*(acc[m][n][rg] - mu)*inv + be_n[n];
      }
    }
  }
}

extern "C" void kernel_launch(void* const* d_in, const int* in_sizes, int n_in,
                              void* d_out, int out_size, void* d_ws, size_t ws_size,
                              hipStream_t stream)
{
  const float* x     = (const float*)d_in[0];
  // d_in[1] = batch_index (block-sorted equal events; unused)
  const float* Ws    = (const float*)d_in[2];
  const float* bs    = (const float*)d_in[3];
  const float* Wh    = (const float*)d_in[4];
  const float* bh    = (const float*)d_in[5];
  const float* Wo    = (const float*)d_in[6];
  const float* bo    = (const float*)d_in[7];
  const float* gamma = (const float*)d_in[8];
  const float* beta  = (const float*)d_in[9];
  float* out = (float*)d_out;

  char* ws = (char*)d_ws;
  float*          sBuf  = (float*)ws;                        // N*4 f32    = 0.5 MB
  uint4*          sfrag = (uint4*)(ws + 524288);             // N*32 B     = 1 MB
  unsigned short* hBuf  = (unsigned short*)(ws + 1572864);   // N*32 bf16  = 2 MB
  unsigned short* Umini = (unsigned short*)(ws + 3670016);   // N*64 bf16  = 4 MB
  unsigned short* WoT   = (unsigned short*)(ws + 7864320);   // 256*320 bf16 = 160 KB

  kA<<<dim3(N_TOT/64 + 10), dim3(256), 0, stream>>>(x, Ws, bs, Wh, bh, Wo,
                                                    sBuf, sfrag, hBuf, (unsigned int*)WoT);
  kB<<<dim3(N_TOT/16), dim3(256), 0, stream>>>(sBuf, sfrag, hBuf, Umini);
  kC<<<dim3(N_TOT/64), dim3(256), 0, stream>>>(Umini, WoT, bo, x, gamma, beta, out);
}